// Round 23
// baseline (330.643 us; speedup 1.0000x reference)
//
#include <hip/hip_runtime.h>
#include <hip/hip_bf16.h>
#include <cmath>

#define D_MODEL 1024
#define N_HEADS 16
#define HEAD_DIM 64
#define SEQ 2048
#define BATCH 2
#define MROWS (BATCH * SEQ)  // 4096

typedef __bf16 bf16;
typedef __bf16 bf16x8 __attribute__((ext_vector_type(8)));
typedef __bf16 bf16x4 __attribute__((ext_vector_type(4)));
typedef float f32x4 __attribute__((ext_vector_type(4)));

// GEMM LDS swizzle (64B rows): byte = row*64 + (cbyte ^ (((row>>1)&3)<<4))
#define SWZG(row, cbyte) ((row) * 64 + ((cbyte) ^ ((((row) >> 1) & 3) << 4)))

// async global->LDS, 16B per lane, linear dest (wave base + lane*16)
#define GLOAD16(g, l)                                                        \
    __builtin_amdgcn_global_load_lds(                                        \
        (const __attribute__((address_space(1))) void*)(g),                  \
        (__attribute__((address_space(3))) void*)(l), 16, 0, 0)

static __device__ __forceinline__ unsigned short bfbits(float f) {
    bf16 b = (bf16)f;
    return *(unsigned short*)&b;
}

// ---------------- fp32 -> bf16 convert (x) ----------------
__global__ __launch_bounds__(256) void cvt_x(const float* __restrict__ x,
                                             bf16* __restrict__ xb) {
    int i = blockIdx.x * 256 + threadIdx.x;
    float4 v = ((const float4*)x)[i];
    bf16x4 o = { (bf16)v.x, (bf16)v.y, (bf16)v.z, (bf16)v.w };
    ((bf16x4*)xb)[i] = o;
}

// ---------------- weight transpose + convert: wt[z][n][k] = W_z[k][n] ----------------
__global__ void cvt_wt(const float* __restrict__ Wq, const float* __restrict__ Wk,
                       const float* __restrict__ Wv, const float* __restrict__ Wo,
                       bf16* __restrict__ wt) {
    __shared__ float tile[32][33];
    int z = blockIdx.z;
    const float* W = (z == 0) ? Wq : (z == 1) ? Wk : (z == 2) ? Wv : Wo;
    int n0 = blockIdx.x * 32, k0 = blockIdx.y * 32;
    int tx = threadIdx.x, ty = threadIdx.y;
    tile[ty][tx] = W[(size_t)(k0 + ty) * D_MODEL + n0 + tx];
    __syncthreads();
    wt[(size_t)z * D_MODEL * D_MODEL + (size_t)(n0 + ty) * D_MODEL + k0 + tx] =
        (bf16)tile[tx][ty];
}

// ---------------- GEMM: Y[M,N] = A[M,K] @ Wt[N,K]^T + bias (R21-proven) ----------------
// Triple-buffered LDS, 2-deep prefetch, counted vmcnt; MODE0 z==2 (V^T)
// epilogue via LDS transpose -> coalesced 256B stores.
template <int MODE>
__global__ __launch_bounds__(256) void gemm_k(const bf16* __restrict__ A,
                                              const bf16* __restrict__ Bt,
                                              const float* __restrict__ b0,
                                              const float* __restrict__ b1,
                                              const float* __restrict__ b2,
                                              void* __restrict__ outp) {
    constexpr int BM = 128, BK = 32, KDIM = D_MODEL;
    __shared__ alignas(16) char SMEM[49152];  // As[3] + Bs[3]; reused as T
    char* Asb = SMEM;
    char* Bsb = SMEM + 24576;
    const int tid = threadIdx.x;
    const int wid = tid >> 6, lane = tid & 63;
    const int m0 = blockIdx.y * BM, n0 = blockIdx.x * BM;
    const int wr = (wid >> 1) * 64, wc = (wid & 1) * 64;
    f32x4 acc[4][4] = {};

#define GSTAGE(K0, BUF)                                                       \
    {                                                                         \
        _Pragma("unroll") for (int c = 0; c < 2; ++c) {                       \
            const int q = c * 4 + wid;                                        \
            const int row = q * 16 + (lane >> 2);                             \
            const int col = (lane & 3) ^ ((row >> 1) & 3);                    \
            GLOAD16(&A[(size_t)(m0 + row) * KDIM + (K0) + col * 8],           \
                    Asb + (BUF) * 8192 + q * 1024);                           \
            GLOAD16(&Bt[(size_t)(n0 + row) * KDIM + (K0) + col * 8],          \
                    Bsb + (BUF) * 8192 + q * 1024);                           \
        }                                                                     \
    }

    GSTAGE(0, 0);
    GSTAGE(BK, 1);
    int cur = 0;
    for (int k0 = 0; k0 < KDIM; k0 += BK) {
        if (k0 + 2 * BK < KDIM) {
            int nb = cur + 2;
            if (nb >= 3) nb -= 3;
            GSTAGE(k0 + 2 * BK, nb);
            asm volatile("s_waitcnt vmcnt(8)" ::: "memory");
        } else if (k0 + BK < KDIM) {
            asm volatile("s_waitcnt vmcnt(4)" ::: "memory");
        } else {
            asm volatile("s_waitcnt vmcnt(0)" ::: "memory");
        }
        __builtin_amdgcn_s_barrier();

        char* Ab = Asb + cur * 8192;
        char* Bb = Bsb + cur * 8192;
        const int cb = (lane >> 4) * 16;
        bf16x8 a[4], b[4];
#pragma unroll
        for (int m = 0; m < 4; ++m) {
            int r = wr + m * 16 + (lane & 15);
            a[m] = *(bf16x8*)(Ab + SWZG(r, cb));
        }
#pragma unroll
        for (int n = 0; n < 4; ++n) {
            int r = wc + n * 16 + (lane & 15);
            b[n] = *(bf16x8*)(Bb + SWZG(r, cb));
        }
#pragma unroll
        for (int m = 0; m < 4; ++m)
#pragma unroll
            for (int n = 0; n < 4; ++n)
                acc[m][n] = __builtin_amdgcn_mfma_f32_16x16x32_bf16(a[m], b[n], acc[m][n], 0, 0, 0);

        __builtin_amdgcn_s_barrier();
        cur = (cur == 2) ? 0 : cur + 1;
    }
#undef GSTAGE

    const int z = n0 >> 10;
    const float* bias = (MODE == 1) ? b0 : ((z == 0) ? b0 : (z == 1) ? b1 : b2);

    if (MODE == 0 && z == 2) {
        // V^T epilogue via LDS transpose: coalesced 256B stores
        bf16* T = (bf16*)SMEM;
#pragma unroll
        for (int m = 0; m < 4; ++m)
#pragma unroll
            for (int n = 0; n < 4; ++n)
#pragma unroll
                for (int r = 0; r < 4; ++r) {
                    int ml = wr + m * 16 + (lane >> 4) * 4 + r;
                    int nl = wc + n * 16 + (lane & 15);
                    float val = acc[m][n][r] + bias[(n0 & 1023) + nl];
                    *(bf16*)((char*)T + nl * 256 + ((2 * ml) ^ ((nl & 7) << 4))) = (bf16)val;
                }
        __builtin_amdgcn_s_barrier();
        const int b_ = m0 >> 11;
        const int s_base = m0 & 2047;
#pragma unroll
        for (int c = 0; c < 8; ++c) {
            int idx = c * 256 + tid;
            int nl = idx >> 4, j = idx & 15;
            bf16x8 v = *(bf16x8*)((char*)T + nl * 256 + ((16 * j) ^ ((nl & 7) << 4)));
            int colN = (n0 & 1023) + nl;
            int head = colN >> 6, hd = colN & 63;
            *(bf16x8*)&((bf16*)outp)[(size_t)2 * 4194304 +
                                     ((size_t)(b_ * N_HEADS + head) * HEAD_DIM + hd) * SEQ +
                                     s_base + 8 * j] = v;
        }
        return;
    }

#pragma unroll
    for (int m = 0; m < 4; ++m)
#pragma unroll
        for (int n = 0; n < 4; ++n)
#pragma unroll
            for (int r = 0; r < 4; ++r) {
                int grow = m0 + wr + m * 16 + (lane >> 4) * 4 + r;
                int gcol = n0 + wc + n * 16 + (lane & 15);
                if (MODE == 0) {
                    int colN = gcol & 1023;
                    float val = acc[m][n][r] + bias[colN];
                    if (z == 0) val *= 0.125f;  // fold attn scale into Q
                    int b_ = grow >> 11, s_ = grow & 2047;
                    int h = colN >> 6, hd = colN & 63;
                    ((bf16*)outp)[(size_t)z * 4194304 +
                                  ((size_t)(b_ * N_HEADS + h) * SEQ + s_) * HEAD_DIM + hd] =
                        (bf16)val;
                } else {
                    float val = acc[m][n][r] + bias[gcol];
                    ((float*)outp)[(size_t)grow * D_MODEL + gcol] = val;
                }
            }
}

// ---------------- flash attention: R21 structure + halved Pk -> 4 blocks/CU ----------------
// grid 512 x 512 threads; block = 128-row band (8 waves x 16 rows); heavy first.
// Double-buffered K/V (R21-proven), counted vmcnt(2), 2 barriers/tile.
// Pk halved to [8][16][16] u32 (8 KB): PV split into two t-phases reusing the
// buffer (wave-private, in-order DS). LDS 40 KB -> 4 blocks/CU (was 3);
// __launch_bounds__(512,8) pins VGPR <= 64 so 32 waves/CU are resident.
// Pk swizzle (16-word rows): sw4=(m&3)<<2; writer word (8tf+2h+rp)^sw4 holds
// t={2w,2w+1}; reader b128 at (4h)^sw4 -> t=8h..8h+7 exactly; banks balanced.
__global__ __launch_bounds__(512, 8) void attn_k(const bf16* __restrict__ Qg,
                                                 const bf16* __restrict__ Kg,
                                                 const bf16* __restrict__ VTg,
                                                 bf16* __restrict__ AO) {
    __shared__ alignas(16) bf16 Ks[2][64 * 64];         // 16 KB
    __shared__ alignas(16) bf16 Vs[2][64 * 64];         // 16 KB
    __shared__ alignas(16) unsigned int Pk[8][16][16];  // 8 KB
    const int tid = threadIdx.x, wid = tid >> 6, lane = tid & 63;
    const int m = lane & 15, h = lane >> 4;
    const int band = 15 - (int)(blockIdx.x >> 5);  // heavy first
    const int bh = blockIdx.x & 31;                // bh%8 fixes XCD -> KV L2 locality
    const int q0 = band * 128 + wid * 16;
    const size_t base = (size_t)bh * SEQ * HEAD_DIM;
    const bf16* VT = VTg + (size_t)bh * HEAD_DIM * SEQ;
    const int sw4 = (m & 3) << 2;
    const int nt_w = band * 2 + (wid >> 2) + 1;  // this wave's tiles
    const int nt_blk = band * 2 + 2;             // block's staged tiles

    bf16x8 aq[2];
#pragma unroll
    for (int kc = 0; kc < 2; ++kc)
        aq[kc] = *(const bf16x8*)
            &Qg[base + (size_t)(q0 + m) * HEAD_DIM + kc * 32 + h * 8];

    f32x4 o[4] = {};
    float mrow = -__builtin_inff();
    float lrow = 0.f;

#define STAGE(T0, BUF)                                                            \
    {                                                                             \
        int row = tid >> 3, sl = tid & 7;                                         \
        GLOAD16(&Kg[base + (size_t)((T0) + row) * HEAD_DIM + 8 * (sl ^ (row & 7))], \
                (char*)&Ks[BUF][0] + tid * 16);                                   \
        GLOAD16(&VT[(size_t)row * SEQ + (T0) + 8 * (sl ^ (row & 7))],             \
                (char*)&Vs[BUF][0] + tid * 16);                                   \
    }

    STAGE(0, 0);
    int cur = 0;
    for (int it = 0; it < nt_blk; ++it) {
        if (it + 1 < nt_blk) {
            STAGE((it + 1) * 64, cur ^ 1);
            asm volatile("s_waitcnt vmcnt(2)" ::: "memory");  // current tile landed
        } else {
            asm volatile("s_waitcnt vmcnt(0)" ::: "memory");
        }
        __builtin_amdgcn_s_barrier();  // all waves' stage of tile it complete

        if (it < nt_w) {
            const int t0 = it * 64;
            char* Kb = (char*)&Ks[cur][0];
            char* Vb = (char*)&Vs[cur][0];
            bf16x8 kf[4][2], vf[4][2];
#pragma unroll
            for (int tf = 0; tf < 4; ++tf)
#pragma unroll
                for (int kc = 0; kc < 2; ++kc)
                    kf[tf][kc] = *(bf16x8*)(Kb + (16 * tf + m) * 128 +
                                            (((4 * kc + h) ^ (m & 7)) << 4));
#pragma unroll
            for (int nf = 0; nf < 4; ++nf)
#pragma unroll
                for (int kc = 0; kc < 2; ++kc)
                    vf[nf][kc] = *(bf16x8*)(Vb + (16 * nf + m) * 128 +
                                            (((4 * kc + h) ^ (m & 7)) << 4));

            // ---- QK^T swapped: lane holds q=m, t=16tf+4h+r ----
            f32x4 s[4];
            __builtin_amdgcn_s_setprio(1);
#pragma unroll
            for (int tf = 0; tf < 4; ++tf) {
                f32x4 z = {};
                z = __builtin_amdgcn_mfma_f32_16x16x32_bf16(kf[tf][0], aq[0], z, 0, 0, 0);
                z = __builtin_amdgcn_mfma_f32_16x16x32_bf16(kf[tf][1], aq[1], z, 0, 0, 0);
                s[tf] = z;
            }
            __builtin_amdgcn_s_setprio(0);

            if (it == nt_w - 1) {
#pragma unroll
                for (int tf = 0; tf < 4; ++tf)
#pragma unroll
                    for (int r = 0; r < 4; ++r) {
                        int gq = q0 + m;
                        int gt = t0 + tf * 16 + h * 4 + r;
                        if (gt > gq) s[tf][r] = -__builtin_inff();
                    }
            }

            // ---- online softmax (per-lane stats, defer-max) ----
            float mx = s[0][0];
#pragma unroll
            for (int tf = 0; tf < 4; ++tf)
#pragma unroll
                for (int r = 0; r < 4; ++r) mx = fmaxf(mx, s[tf][r]);
            mx = fmaxf(mx, __shfl_xor(mx, 16));
            mx = fmaxf(mx, __shfl_xor(mx, 32));
            if (!__all(mx <= mrow + 8.f)) {
                float mn = fmaxf(mrow, mx);
                float sf = __expf(mrow - mn);
                mrow = mn;
                lrow *= sf;
                float sfr[4];
#pragma unroll
                for (int r = 0; r < 4; ++r) sfr[r] = __shfl(sf, 20 * h + r);
#pragma unroll
                for (int nf = 0; nf < 4; ++nf)
#pragma unroll
                    for (int r = 0; r < 4; ++r) o[nf][r] *= sfr[r];
            }
            float rs = 0.f;
#pragma unroll
            for (int tf = 0; tf < 4; ++tf)
#pragma unroll
                for (int r = 0; r < 4; ++r) {
                    float pv = __expf(s[tf][r] - mrow);
                    s[tf][r] = pv;
                    rs += pv;
                }
            rs += __shfl_xor(rs, 16);
            rs += __shfl_xor(rs, 32);
            lrow += rs;

            // ---- PV in two t-phases through the halved Pk buffer ----
            __builtin_amdgcn_s_setprio(1);
#pragma unroll
            for (int ph = 0; ph < 2; ++ph) {
#pragma unroll
                for (int tf = 0; tf < 2; ++tf)
#pragma unroll
                    for (int rp = 0; rp < 2; ++rp) {
                        int tfa = 2 * ph + tf;
                        unsigned int w =
                            ((unsigned int)bfbits(s[tfa][2 * rp + 1]) << 16) |
                            bfbits(s[tfa][2 * rp]);
                        Pk[wid][m][(8 * tf + 2 * h + rp) ^ sw4] = w;
                    }
                bf16x8 ap = *(bf16x8*)&Pk[wid][m][(4 * h) ^ sw4];
#pragma unroll
                for (int nf = 0; nf < 4; ++nf)
                    o[nf] = __builtin_amdgcn_mfma_f32_16x16x32_bf16(
                        ap, vf[nf][ph], o[nf], 0, 0, 0);
            }
            __builtin_amdgcn_s_setprio(0);
        }
        __builtin_amdgcn_s_barrier();  // all reads of buf[cur] done; safe to overwrite
        cur ^= 1;
    }
#undef STAGE

    // ---- direct write-out (no merge: waves own distinct q-rows) ----
    const int b_ = bh >> 4, hh = bh & 15;
    float lcr[4];
#pragma unroll
    for (int r = 0; r < 4; ++r) lcr[r] = __shfl(lrow, 20 * h + r);
#pragma unroll
    for (int nf = 0; nf < 4; ++nf)
#pragma unroll
        for (int r = 0; r < 4; ++r) {
            float val = o[nf][r] / lcr[r];
            int s_ = q0 + h * 4 + r;
            AO[((size_t)(b_ * SEQ + s_)) * D_MODEL + hh * HEAD_DIM + nf * 16 + m] =
                (bf16)val;
        }
}

extern "C" void kernel_launch(void* const* d_in, const int* in_sizes, int n_in,
                              void* d_out, int out_size, void* d_ws, size_t ws_size,
                              hipStream_t stream) {
    const float* x  = (const float*)d_in[0];
    const float* Wq = (const float*)d_in[1];
    const float* bq = (const float*)d_in[2];
    const float* Wk = (const float*)d_in[3];
    const float* bk = (const float*)d_in[4];
    const float* Wv = (const float*)d_in[5];
    const float* bv = (const float*)d_in[6];
    const float* Wo = (const float*)d_in[7];
    const float* bo = (const float*)d_in[8];

    char* ws = (char*)d_ws;
    const size_t MB = 1u << 20;
    bf16* wt = (bf16*)ws;                  // 4 x [1024][1024] bf16 (QKV contiguous)
    bf16* xb = (bf16*)(ws + 8 * MB);       // [4096][1024] bf16
    bf16* Qb = (bf16*)(ws + 16 * MB);      // Q*0.125 [32][2048][64]; K; V^T [32][64][2048]
    bf16* AO = (bf16*)(ws + 40 * MB);      // [4096][1024] bf16

    const size_t WSTRIDE = (size_t)D_MODEL * D_MODEL;

    cvt_x<<<dim3(MROWS * D_MODEL / 4 / 256), dim3(256), 0, stream>>>(x, xb);
    cvt_wt<<<dim3(32, 32, 4), dim3(32, 32), 0, stream>>>(Wq, Wk, Wv, Wo, wt);

    gemm_k<0><<<dim3(24, 32), dim3(256), 0, stream>>>(xb, wt, bq, bk, bv, Qb);

    bf16* Kb = Qb + 4194304;
    bf16* VTb = Qb + 2 * 4194304;
    attn_k<<<dim3(512), dim3(512), 0, stream>>>(Qb, Kb, VTb, AO);

    gemm_k<1><<<dim3(8, 32), dim3(256), 0, stream>>>(AO, wt + 3 * WSTRIDE, bo, bo, bo, d_out);
}

// Round 24
// 115.236 us; speedup vs baseline: 2.8693x; 2.8693x over previous
//
#include <hip/hip_runtime.h>
#include <hip/hip_bf16.h>
#include <cmath>

#define D_MODEL 1024
#define N_HEADS 16
#define HEAD_DIM 64
#define SEQ 2048
#define BATCH 2
#define MROWS (BATCH * SEQ)  // 4096

typedef __bf16 bf16;
typedef __bf16 bf16x8 __attribute__((ext_vector_type(8)));
typedef __bf16 bf16x4 __attribute__((ext_vector_type(4)));
typedef float f32x4 __attribute__((ext_vector_type(4)));

// GEMM LDS swizzle (64B rows): byte = row*64 + (cbyte ^ (((row>>1)&3)<<4))
#define SWZG(row, cbyte) ((row) * 64 + ((cbyte) ^ ((((row) >> 1) & 3) << 4)))

// async global->LDS, 16B per lane, linear dest (wave base + lane*16)
#define GLOAD16(g, l)                                                        \
    __builtin_amdgcn_global_load_lds(                                        \
        (const __attribute__((address_space(1))) void*)(g),                  \
        (__attribute__((address_space(3))) void*)(l), 16, 0, 0)

static __device__ __forceinline__ unsigned short bfbits(float f) {
    bf16 b = (bf16)f;
    return *(unsigned short*)&b;
}

// ---------------- fp32 -> bf16 convert (x) ----------------
__global__ __launch_bounds__(256) void cvt_x(const float* __restrict__ x,
                                             bf16* __restrict__ xb) {
    int i = blockIdx.x * 256 + threadIdx.x;
    float4 v = ((const float4*)x)[i];
    bf16x4 o = { (bf16)v.x, (bf16)v.y, (bf16)v.z, (bf16)v.w };
    ((bf16x4*)xb)[i] = o;
}

// ---------------- weight transpose + convert: wt[z][n][k] = W_z[k][n] ----------------
__global__ void cvt_wt(const float* __restrict__ Wq, const float* __restrict__ Wk,
                       const float* __restrict__ Wv, const float* __restrict__ Wo,
                       bf16* __restrict__ wt) {
    __shared__ float tile[32][33];
    int z = blockIdx.z;
    const float* W = (z == 0) ? Wq : (z == 1) ? Wk : (z == 2) ? Wv : Wo;
    int n0 = blockIdx.x * 32, k0 = blockIdx.y * 32;
    int tx = threadIdx.x, ty = threadIdx.y;
    tile[ty][tx] = W[(size_t)(k0 + ty) * D_MODEL + n0 + tx];
    __syncthreads();
    wt[(size_t)z * D_MODEL * D_MODEL + (size_t)(n0 + ty) * D_MODEL + k0 + tx] =
        (bf16)tile[tx][ty];
}

// ---------------- GEMM: Y[M,N] = A[M,K] @ Wt[N,K]^T + bias (R21-proven) ----------------
// Triple-buffered LDS, 2-deep prefetch, counted vmcnt; MODE0 z==2 (V^T)
// epilogue via LDS transpose -> coalesced 256B stores.
template <int MODE>
__global__ __launch_bounds__(256) void gemm_k(const bf16* __restrict__ A,
                                              const bf16* __restrict__ Bt,
                                              const float* __restrict__ b0,
                                              const float* __restrict__ b1,
                                              const float* __restrict__ b2,
                                              void* __restrict__ outp) {
    constexpr int BM = 128, BK = 32, KDIM = D_MODEL;
    __shared__ alignas(16) char SMEM[49152];  // As[3] + Bs[3]; reused as T
    char* Asb = SMEM;
    char* Bsb = SMEM + 24576;
    const int tid = threadIdx.x;
    const int wid = tid >> 6, lane = tid & 63;
    const int m0 = blockIdx.y * BM, n0 = blockIdx.x * BM;
    const int wr = (wid >> 1) * 64, wc = (wid & 1) * 64;
    f32x4 acc[4][4] = {};

#define GSTAGE(K0, BUF)                                                       \
    {                                                                         \
        _Pragma("unroll") for (int c = 0; c < 2; ++c) {                       \
            const int q = c * 4 + wid;                                        \
            const int row = q * 16 + (lane >> 2);                             \
            const int col = (lane & 3) ^ ((row >> 1) & 3);                    \
            GLOAD16(&A[(size_t)(m0 + row) * KDIM + (K0) + col * 8],           \
                    Asb + (BUF) * 8192 + q * 1024);                           \
            GLOAD16(&Bt[(size_t)(n0 + row) * KDIM + (K0) + col * 8],          \
                    Bsb + (BUF) * 8192 + q * 1024);                           \
        }                                                                     \
    }

    GSTAGE(0, 0);
    GSTAGE(BK, 1);
    int cur = 0;
    for (int k0 = 0; k0 < KDIM; k0 += BK) {
        if (k0 + 2 * BK < KDIM) {
            int nb = cur + 2;
            if (nb >= 3) nb -= 3;
            GSTAGE(k0 + 2 * BK, nb);
            asm volatile("s_waitcnt vmcnt(8)" ::: "memory");
        } else if (k0 + BK < KDIM) {
            asm volatile("s_waitcnt vmcnt(4)" ::: "memory");
        } else {
            asm volatile("s_waitcnt vmcnt(0)" ::: "memory");
        }
        __builtin_amdgcn_s_barrier();

        char* Ab = Asb + cur * 8192;
        char* Bb = Bsb + cur * 8192;
        const int cb = (lane >> 4) * 16;
        bf16x8 a[4], b[4];
#pragma unroll
        for (int m = 0; m < 4; ++m) {
            int r = wr + m * 16 + (lane & 15);
            a[m] = *(bf16x8*)(Ab + SWZG(r, cb));
        }
#pragma unroll
        for (int n = 0; n < 4; ++n) {
            int r = wc + n * 16 + (lane & 15);
            b[n] = *(bf16x8*)(Bb + SWZG(r, cb));
        }
#pragma unroll
        for (int m = 0; m < 4; ++m)
#pragma unroll
            for (int n = 0; n < 4; ++n)
                acc[m][n] = __builtin_amdgcn_mfma_f32_16x16x32_bf16(a[m], b[n], acc[m][n], 0, 0, 0);

        __builtin_amdgcn_s_barrier();
        cur = (cur == 2) ? 0 : cur + 1;
    }
#undef GSTAGE

    const int z = n0 >> 10;
    const float* bias = (MODE == 1) ? b0 : ((z == 0) ? b0 : (z == 1) ? b1 : b2);

    if (MODE == 0 && z == 2) {
        // V^T epilogue via LDS transpose: coalesced 256B stores
        bf16* T = (bf16*)SMEM;
#pragma unroll
        for (int m = 0; m < 4; ++m)
#pragma unroll
            for (int n = 0; n < 4; ++n)
#pragma unroll
                for (int r = 0; r < 4; ++r) {
                    int ml = wr + m * 16 + (lane >> 4) * 4 + r;
                    int nl = wc + n * 16 + (lane & 15);
                    float val = acc[m][n][r] + bias[(n0 & 1023) + nl];
                    *(bf16*)((char*)T + nl * 256 + ((2 * ml) ^ ((nl & 7) << 4))) = (bf16)val;
                }
        __builtin_amdgcn_s_barrier();
        const int b_ = m0 >> 11;
        const int s_base = m0 & 2047;
#pragma unroll
        for (int c = 0; c < 8; ++c) {
            int idx = c * 256 + tid;
            int nl = idx >> 4, j = idx & 15;
            bf16x8 v = *(bf16x8*)((char*)T + nl * 256 + ((16 * j) ^ ((nl & 7) << 4)));
            int colN = (n0 & 1023) + nl;
            int head = colN >> 6, hd = colN & 63;
            *(bf16x8*)&((bf16*)outp)[(size_t)2 * 4194304 +
                                     ((size_t)(b_ * N_HEADS + head) * HEAD_DIM + hd) * SEQ +
                                     s_base + 8 * j] = v;
        }
        return;
    }

#pragma unroll
    for (int m = 0; m < 4; ++m)
#pragma unroll
        for (int n = 0; n < 4; ++n)
#pragma unroll
            for (int r = 0; r < 4; ++r) {
                int grow = m0 + wr + m * 16 + (lane >> 4) * 4 + r;
                int gcol = n0 + wc + n * 16 + (lane & 15);
                if (MODE == 0) {
                    int colN = gcol & 1023;
                    float val = acc[m][n][r] + bias[colN];
                    if (z == 0) val *= 0.125f;  // fold attn scale into Q
                    int b_ = grow >> 11, s_ = grow & 2047;
                    int h = colN >> 6, hd = colN & 63;
                    ((bf16*)outp)[(size_t)z * 4194304 +
                                  ((size_t)(b_ * N_HEADS + h) * SEQ + s_) * HEAD_DIM + hd] =
                        (bf16)val;
                } else {
                    float val = acc[m][n][r] + bias[gcol];
                    ((float*)outp)[(size_t)grow * D_MODEL + gcol] = val;
                }
            }
}

// ---------------- flash attention: R21 structure, Pk halved (8 KB) -> 40 KB LDS ----------------
// grid 512 x 512 threads; block = 128-row band (8 waves x 16 rows); heavy first.
// Double-buffered K/V (proven), counted vmcnt(2), 2 barriers/tile. PV split in
// two t-phases through the halved wave-private Pk (correctness proven R23).
// NO waves-per-EU pin (R23 lesson: pinning forced VGPR 32 -> 550MB scratch
// spill). Natural VGPR ~64 + 40KB LDS -> 4 blocks/CU, 32 waves/CU.
// Pk swizzle (16-word rows): sw4=(m&3)<<2; writer word (8tf+2h+rp)^sw4 holds
// t={2w,2w+1}; reader b128 at (4h)^sw4 -> t=8h..8h+7 exactly; banks balanced.
__global__ __launch_bounds__(512) void attn_k(const bf16* __restrict__ Qg,
                                              const bf16* __restrict__ Kg,
                                              const bf16* __restrict__ VTg,
                                              bf16* __restrict__ AO) {
    __shared__ alignas(16) bf16 Ks[2][64 * 64];         // 16 KB
    __shared__ alignas(16) bf16 Vs[2][64 * 64];         // 16 KB
    __shared__ alignas(16) unsigned int Pk[8][16][16];  // 8 KB
    const int tid = threadIdx.x, wid = tid >> 6, lane = tid & 63;
    const int m = lane & 15, h = lane >> 4;
    const int band = 15 - (int)(blockIdx.x >> 5);  // heavy first
    const int bh = blockIdx.x & 31;                // bh%8 fixes XCD -> KV L2 locality
    const int q0 = band * 128 + wid * 16;
    const size_t base = (size_t)bh * SEQ * HEAD_DIM;
    const bf16* VT = VTg + (size_t)bh * HEAD_DIM * SEQ;
    const int sw4 = (m & 3) << 2;
    const int nt_w = band * 2 + (wid >> 2) + 1;  // this wave's tiles
    const int nt_blk = band * 2 + 2;             // block's staged tiles

    bf16x8 aq[2];
#pragma unroll
    for (int kc = 0; kc < 2; ++kc)
        aq[kc] = *(const bf16x8*)
            &Qg[base + (size_t)(q0 + m) * HEAD_DIM + kc * 32 + h * 8];

    f32x4 o[4] = {};
    float mrow = -__builtin_inff();
    float lrow = 0.f;

#define STAGE(T0, BUF)                                                            \
    {                                                                             \
        int row = tid >> 3, sl = tid & 7;                                         \
        GLOAD16(&Kg[base + (size_t)((T0) + row) * HEAD_DIM + 8 * (sl ^ (row & 7))], \
                (char*)&Ks[BUF][0] + tid * 16);                                   \
        GLOAD16(&VT[(size_t)row * SEQ + (T0) + 8 * (sl ^ (row & 7))],             \
                (char*)&Vs[BUF][0] + tid * 16);                                   \
    }

    STAGE(0, 0);
    int cur = 0;
    for (int it = 0; it < nt_blk; ++it) {
        if (it + 1 < nt_blk) {
            STAGE((it + 1) * 64, cur ^ 1);
            asm volatile("s_waitcnt vmcnt(2)" ::: "memory");  // current tile landed
        } else {
            asm volatile("s_waitcnt vmcnt(0)" ::: "memory");
        }
        __builtin_amdgcn_s_barrier();  // all waves' stage of tile it complete

        if (it < nt_w) {
            const int t0 = it * 64;
            char* Kb = (char*)&Ks[cur][0];
            char* Vb = (char*)&Vs[cur][0];
            bf16x8 kf[4][2], vf[4][2];
#pragma unroll
            for (int tf = 0; tf < 4; ++tf)
#pragma unroll
                for (int kc = 0; kc < 2; ++kc)
                    kf[tf][kc] = *(bf16x8*)(Kb + (16 * tf + m) * 128 +
                                            (((4 * kc + h) ^ (m & 7)) << 4));
#pragma unroll
            for (int nf = 0; nf < 4; ++nf)
#pragma unroll
                for (int kc = 0; kc < 2; ++kc)
                    vf[nf][kc] = *(bf16x8*)(Vb + (16 * nf + m) * 128 +
                                            (((4 * kc + h) ^ (m & 7)) << 4));

            // ---- QK^T swapped: lane holds q=m, t=16tf+4h+r ----
            f32x4 s[4];
            __builtin_amdgcn_s_setprio(1);
#pragma unroll
            for (int tf = 0; tf < 4; ++tf) {
                f32x4 z = {};
                z = __builtin_amdgcn_mfma_f32_16x16x32_bf16(kf[tf][0], aq[0], z, 0, 0, 0);
                z = __builtin_amdgcn_mfma_f32_16x16x32_bf16(kf[tf][1], aq[1], z, 0, 0, 0);
                s[tf] = z;
            }
            __builtin_amdgcn_s_setprio(0);

            if (it == nt_w - 1) {
#pragma unroll
                for (int tf = 0; tf < 4; ++tf)
#pragma unroll
                    for (int r = 0; r < 4; ++r) {
                        int gq = q0 + m;
                        int gt = t0 + tf * 16 + h * 4 + r;
                        if (gt > gq) s[tf][r] = -__builtin_inff();
                    }
            }

            // ---- online softmax (per-lane stats, defer-max) ----
            float mx = s[0][0];
#pragma unroll
            for (int tf = 0; tf < 4; ++tf)
#pragma unroll
                for (int r = 0; r < 4; ++r) mx = fmaxf(mx, s[tf][r]);
            mx = fmaxf(mx, __shfl_xor(mx, 16));
            mx = fmaxf(mx, __shfl_xor(mx, 32));
            if (!__all(mx <= mrow + 8.f)) {
                float mn = fmaxf(mrow, mx);
                float sf = __expf(mrow - mn);
                mrow = mn;
                lrow *= sf;
                float sfr[4];
#pragma unroll
                for (int r = 0; r < 4; ++r) sfr[r] = __shfl(sf, 20 * h + r);
#pragma unroll
                for (int nf = 0; nf < 4; ++nf)
#pragma unroll
                    for (int r = 0; r < 4; ++r) o[nf][r] *= sfr[r];
            }
            float rs = 0.f;
#pragma unroll
            for (int tf = 0; tf < 4; ++tf)
#pragma unroll
                for (int r = 0; r < 4; ++r) {
                    float pv = __expf(s[tf][r] - mrow);
                    s[tf][r] = pv;
                    rs += pv;
                }
            rs += __shfl_xor(rs, 16);
            rs += __shfl_xor(rs, 32);
            lrow += rs;

            // ---- PV in two t-phases through the halved Pk buffer ----
            __builtin_amdgcn_s_setprio(1);
#pragma unroll
            for (int ph = 0; ph < 2; ++ph) {
#pragma unroll
                for (int tf = 0; tf < 2; ++tf)
#pragma unroll
                    for (int rp = 0; rp < 2; ++rp) {
                        int tfa = 2 * ph + tf;
                        unsigned int w =
                            ((unsigned int)bfbits(s[tfa][2 * rp + 1]) << 16) |
                            bfbits(s[tfa][2 * rp]);
                        Pk[wid][m][(8 * tf + 2 * h + rp) ^ sw4] = w;
                    }
                bf16x8 ap = *(bf16x8*)&Pk[wid][m][(4 * h) ^ sw4];
#pragma unroll
                for (int nf = 0; nf < 4; ++nf)
                    o[nf] = __builtin_amdgcn_mfma_f32_16x16x32_bf16(
                        ap, vf[nf][ph], o[nf], 0, 0, 0);
            }
            __builtin_amdgcn_s_setprio(0);
        }
        __builtin_amdgcn_s_barrier();  // all reads of buf[cur] done; safe to overwrite
        cur ^= 1;
    }
#undef STAGE

    // ---- direct write-out (no merge: waves own distinct q-rows) ----
    const int b_ = bh >> 4, hh = bh & 15;
    float lcr[4];
#pragma unroll
    for (int r = 0; r < 4; ++r) lcr[r] = __shfl(lrow, 20 * h + r);
#pragma unroll
    for (int nf = 0; nf < 4; ++nf)
#pragma unroll
        for (int r = 0; r < 4; ++r) {
            float val = o[nf][r] / lcr[r];
            int s_ = q0 + h * 4 + r;
            AO[((size_t)(b_ * SEQ + s_)) * D_MODEL + hh * HEAD_DIM + nf * 16 + m] =
                (bf16)val;
        }
}

extern "C" void kernel_launch(void* const* d_in, const int* in_sizes, int n_in,
                              void* d_out, int out_size, void* d_ws, size_t ws_size,
                              hipStream_t stream) {
    const float* x  = (const float*)d_in[0];
    const float* Wq = (const float*)d_in[1];
    const float* bq = (const float*)d_in[2];
    const float* Wk = (const float*)d_in[3];
    const float* bk = (const float*)d_in[4];
    const float* Wv = (const float*)d_in[5];
    const float* bv = (const float*)d_in[6];
    const float* Wo = (const float*)d_in[7];
    const float* bo = (const float*)d_in[8];

    char* ws = (char*)d_ws;
    const size_t MB = 1u << 20;
    bf16* wt = (bf16*)ws;                  // 4 x [1024][1024] bf16 (QKV contiguous)
    bf16* xb = (bf16*)(ws + 8 * MB);       // [4096][1024] bf16
    bf16* Qb = (bf16*)(ws + 16 * MB);      // Q*0.125 [32][2048][64]; K; V^T [32][64][2048]
    bf16* AO = (bf16*)(ws + 40 * MB);      // [4096][1024] bf16

    const size_t WSTRIDE = (size_t)D_MODEL * D_MODEL;

    cvt_x<<<dim3(MROWS * D_MODEL / 4 / 256), dim3(256), 0, stream>>>(x, xb);
    cvt_wt<<<dim3(32, 32, 4), dim3(32, 32), 0, stream>>>(Wq, Wk, Wv, Wo, wt);

    gemm_k<0><<<dim3(24, 32), dim3(256), 0, stream>>>(xb, wt, bq, bk, bv, Qb);

    bf16* Kb = Qb + 4194304;
    bf16* VTb = Qb + 2 * 4194304;
    attn_k<<<dim3(512), dim3(512), 0, stream>>>(Qb, Kb, VTb, AO);

    gemm_k<1><<<dim3(8, 32), dim3(256), 0, stream>>>(AO, wt + 3 * WSTRIDE, bo, bo, bo, d_out);
}

// Round 25
// 111.269 us; speedup vs baseline: 2.9716x; 1.0357x over previous
//
#include <hip/hip_runtime.h>
#include <hip/hip_bf16.h>
#include <cmath>

#define D_MODEL 1024
#define N_HEADS 16
#define HEAD_DIM 64
#define SEQ 2048
#define BATCH 2
#define MROWS (BATCH * SEQ)  // 4096

typedef __bf16 bf16;
typedef __bf16 bf16x8 __attribute__((ext_vector_type(8)));
typedef __bf16 bf16x4 __attribute__((ext_vector_type(4)));
typedef float f32x4 __attribute__((ext_vector_type(4)));

// GEMM LDS swizzle (64B rows): byte = row*64 + (cbyte ^ (((row>>1)&3)<<4))
#define SWZG(row, cbyte) ((row) * 64 + ((cbyte) ^ ((((row) >> 1) & 3) << 4)))

// async global->LDS, 16B per lane, linear dest (wave base + lane*16)
#define GLOAD16(g, l)                                                        \
    __builtin_amdgcn_global_load_lds(                                        \
        (const __attribute__((address_space(1))) void*)(g),                  \
        (__attribute__((address_space(3))) void*)(l), 16, 0, 0)

static __device__ __forceinline__ unsigned short bfbits(float f) {
    bf16 b = (bf16)f;
    return *(unsigned short*)&b;
}

// ---------------- fp32 -> bf16 convert (x) ----------------
__global__ __launch_bounds__(256) void cvt_x(const float* __restrict__ x,
                                             bf16* __restrict__ xb) {
    int i = blockIdx.x * 256 + threadIdx.x;
    float4 v = ((const float4*)x)[i];
    bf16x4 o = { (bf16)v.x, (bf16)v.y, (bf16)v.z, (bf16)v.w };
    ((bf16x4*)xb)[i] = o;
}

// ---------------- weight transpose + convert: wt[z][n][k] = W_z[k][n] ----------------
__global__ void cvt_wt(const float* __restrict__ Wq, const float* __restrict__ Wk,
                       const float* __restrict__ Wv, const float* __restrict__ Wo,
                       bf16* __restrict__ wt) {
    __shared__ float tile[32][33];
    int z = blockIdx.z;
    const float* W = (z == 0) ? Wq : (z == 1) ? Wk : (z == 2) ? Wv : Wo;
    int n0 = blockIdx.x * 32, k0 = blockIdx.y * 32;
    int tx = threadIdx.x, ty = threadIdx.y;
    tile[ty][tx] = W[(size_t)(k0 + ty) * D_MODEL + n0 + tx];
    __syncthreads();
    wt[(size_t)z * D_MODEL * D_MODEL + (size_t)(n0 + ty) * D_MODEL + k0 + tx] =
        (bf16)tile[tx][ty];
}

// ---------------- GEMM: Y[M,N] = A[M,K] @ Wt[N,K]^T + bias (R21-proven) ----------------
// Triple-buffered LDS, 2-deep prefetch, counted vmcnt; MODE0 z==2 (V^T)
// epilogue via LDS transpose -> coalesced 256B stores.
template <int MODE>
__global__ __launch_bounds__(256) void gemm_k(const bf16* __restrict__ A,
                                              const bf16* __restrict__ Bt,
                                              const float* __restrict__ b0,
                                              const float* __restrict__ b1,
                                              const float* __restrict__ b2,
                                              void* __restrict__ outp) {
    constexpr int BM = 128, BK = 32, KDIM = D_MODEL;
    __shared__ alignas(16) char SMEM[49152];  // As[3] + Bs[3]; reused as T
    char* Asb = SMEM;
    char* Bsb = SMEM + 24576;
    const int tid = threadIdx.x;
    const int wid = tid >> 6, lane = tid & 63;
    const int m0 = blockIdx.y * BM, n0 = blockIdx.x * BM;
    const int wr = (wid >> 1) * 64, wc = (wid & 1) * 64;
    f32x4 acc[4][4] = {};

#define GSTAGE(K0, BUF)                                                       \
    {                                                                         \
        _Pragma("unroll") for (int c = 0; c < 2; ++c) {                       \
            const int q = c * 4 + wid;                                        \
            const int row = q * 16 + (lane >> 2);                             \
            const int col = (lane & 3) ^ ((row >> 1) & 3);                    \
            GLOAD16(&A[(size_t)(m0 + row) * KDIM + (K0) + col * 8],           \
                    Asb + (BUF) * 8192 + q * 1024);                           \
            GLOAD16(&Bt[(size_t)(n0 + row) * KDIM + (K0) + col * 8],          \
                    Bsb + (BUF) * 8192 + q * 1024);                           \
        }                                                                     \
    }

    GSTAGE(0, 0);
    GSTAGE(BK, 1);
    int cur = 0;
    for (int k0 = 0; k0 < KDIM; k0 += BK) {
        if (k0 + 2 * BK < KDIM) {
            int nb = cur + 2;
            if (nb >= 3) nb -= 3;
            GSTAGE(k0 + 2 * BK, nb);
            asm volatile("s_waitcnt vmcnt(8)" ::: "memory");
        } else if (k0 + BK < KDIM) {
            asm volatile("s_waitcnt vmcnt(4)" ::: "memory");
        } else {
            asm volatile("s_waitcnt vmcnt(0)" ::: "memory");
        }
        __builtin_amdgcn_s_barrier();

        char* Ab = Asb + cur * 8192;
        char* Bb = Bsb + cur * 8192;
        const int cb = (lane >> 4) * 16;
        bf16x8 a[4], b[4];
#pragma unroll
        for (int m = 0; m < 4; ++m) {
            int r = wr + m * 16 + (lane & 15);
            a[m] = *(bf16x8*)(Ab + SWZG(r, cb));
        }
#pragma unroll
        for (int n = 0; n < 4; ++n) {
            int r = wc + n * 16 + (lane & 15);
            b[n] = *(bf16x8*)(Bb + SWZG(r, cb));
        }
#pragma unroll
        for (int m = 0; m < 4; ++m)
#pragma unroll
            for (int n = 0; n < 4; ++n)
                acc[m][n] = __builtin_amdgcn_mfma_f32_16x16x32_bf16(a[m], b[n], acc[m][n], 0, 0, 0);

        __builtin_amdgcn_s_barrier();
        cur = (cur == 2) ? 0 : cur + 1;
    }
#undef GSTAGE

    const int z = n0 >> 10;
    const float* bias = (MODE == 1) ? b0 : ((z == 0) ? b0 : (z == 1) ? b1 : b2);

    if (MODE == 0 && z == 2) {
        // V^T epilogue via LDS transpose: coalesced 256B stores
        bf16* T = (bf16*)SMEM;
#pragma unroll
        for (int m = 0; m < 4; ++m)
#pragma unroll
            for (int n = 0; n < 4; ++n)
#pragma unroll
                for (int r = 0; r < 4; ++r) {
                    int ml = wr + m * 16 + (lane >> 4) * 4 + r;
                    int nl = wc + n * 16 + (lane & 15);
                    float val = acc[m][n][r] + bias[(n0 & 1023) + nl];
                    *(bf16*)((char*)T + nl * 256 + ((2 * ml) ^ ((nl & 7) << 4))) = (bf16)val;
                }
        __builtin_amdgcn_s_barrier();
        const int b_ = m0 >> 11;
        const int s_base = m0 & 2047;
#pragma unroll
        for (int c = 0; c < 8; ++c) {
            int idx = c * 256 + tid;
            int nl = idx >> 4, j = idx & 15;
            bf16x8 v = *(bf16x8*)((char*)T + nl * 256 + ((16 * j) ^ ((nl & 7) << 4)));
            int colN = (n0 & 1023) + nl;
            int head = colN >> 6, hd = colN & 63;
            *(bf16x8*)&((bf16*)outp)[(size_t)2 * 4194304 +
                                     ((size_t)(b_ * N_HEADS + head) * HEAD_DIM + hd) * SEQ +
                                     s_base + 8 * j] = v;
        }
        return;
    }

#pragma unroll
    for (int m = 0; m < 4; ++m)
#pragma unroll
        for (int n = 0; n < 4; ++n)
#pragma unroll
            for (int r = 0; r < 4; ++r) {
                int grow = m0 + wr + m * 16 + (lane >> 4) * 4 + r;
                int gcol = n0 + wc + n * 16 + (lane & 15);
                if (MODE == 0) {
                    int colN = gcol & 1023;
                    float val = acc[m][n][r] + bias[colN];
                    if (z == 0) val *= 0.125f;  // fold attn scale into Q
                    int b_ = grow >> 11, s_ = grow & 2047;
                    int h = colN >> 6, hd = colN & 63;
                    ((bf16*)outp)[(size_t)z * 4194304 +
                                  ((size_t)(b_ * N_HEADS + h) * SEQ + s_) * HEAD_DIM + hd] =
                        (bf16)val;
                } else {
                    float val = acc[m][n][r] + bias[gcol];
                    ((float*)outp)[(size_t)grow * D_MODEL + gcol] = val;
                }
            }
}

// ---------------- flash attention: 64-row half-bands, constant per-CU work ----------------
// grid 1024 x 256 threads (4 waves x 16 rows = 64-row half-band hb in 0..31,
// work = hb+1 tiles; all 4 waves share the same nt -> no intra-block tail).
// Quarter-interleaved hb order: q0: 31-a, q1: 23-a, q2: 8+a, q3: a  (a=(idx>>5)&7)
// -> any stride-256 co-resident quadruple sums to 62 (constant per-CU work),
// and global order is heavy-first (LPT fallback). LDS 40KB -> all 1024 resident
// (4/CU); 4096 waves = 16/CU, same TLP as before, max chain 32 -> 17 tiles.
// Proven R18/R21 body: double-buffered K/V, counted vmcnt(4), 2 barriers/tile,
// swapped QK^T, per-lane softmax, one-phase packed-P PV.
__global__ __launch_bounds__(256) void attn_k(const bf16* __restrict__ Qg,
                                              const bf16* __restrict__ Kg,
                                              const bf16* __restrict__ VTg,
                                              bf16* __restrict__ AO) {
    __shared__ alignas(16) bf16 Ks[2][64 * 64];         // 16 KB
    __shared__ alignas(16) bf16 Vs[2][64 * 64];         // 16 KB
    __shared__ alignas(16) unsigned int Pk[4][16][32];  // 8 KB
    const int tid = threadIdx.x, wid = tid >> 6, lane = tid & 63;
    const int m = lane & 15, h = lane >> 4;
    const int idx = blockIdx.x;
    const int bh = idx & 31;                // bh%8 fixes XCD -> KV L2 locality
    const int a = (idx >> 5) & 7;
    const int qd = idx >> 8;
    const int hb = (qd == 0) ? (31 - a) : (qd == 1) ? (23 - a) : (qd == 2) ? (8 + a) : a;
    const int q0 = hb * 64 + wid * 16;
    const size_t base = (size_t)bh * SEQ * HEAD_DIM;
    const bf16* VT = VTg + (size_t)bh * HEAD_DIM * SEQ;
    const int swz = (m & 7) << 2;
    const int nt = hb + 1;  // same for all waves in the block

    bf16x8 aq[2];
#pragma unroll
    for (int kc = 0; kc < 2; ++kc)
        aq[kc] = *(const bf16x8*)
            &Qg[base + (size_t)(q0 + m) * HEAD_DIM + kc * 32 + h * 8];

    f32x4 o[4] = {};
    float mrow = -__builtin_inff();
    float lrow = 0.f;

    // stage tile T0 into buffer BUF: 2 K + 2 V GLOAD16 per thread (256 threads).
#define STAGE(T0, BUF)                                                            \
    {                                                                             \
        _Pragma("unroll") for (int c = 0; c < 2; ++c) {                           \
            int chunk = c * 256 + tid;                                            \
            int row = chunk >> 3, sl = chunk & 7;                                 \
            GLOAD16(&Kg[base + (size_t)((T0) + row) * HEAD_DIM +                  \
                        8 * (sl ^ (row & 7))],                                    \
                    (char*)&Ks[BUF][0] + chunk * 16);                             \
            GLOAD16(&VT[(size_t)row * SEQ + (T0) + 8 * (sl ^ (row & 7))],         \
                    (char*)&Vs[BUF][0] + chunk * 16);                             \
        }                                                                         \
    }

    STAGE(0, 0);
    int cur = 0;
    for (int it = 0; it < nt; ++it) {
        if (it + 1 < nt) {
            STAGE((it + 1) * 64, cur ^ 1);
            asm volatile("s_waitcnt vmcnt(4)" ::: "memory");  // current tile landed
        } else {
            asm volatile("s_waitcnt vmcnt(0)" ::: "memory");
        }
        __builtin_amdgcn_s_barrier();  // all waves' stage of tile it complete

        {
            const int t0 = it * 64;
            char* Kb = (char*)&Ks[cur][0];
            char* Vb = (char*)&Vs[cur][0];
            bf16x8 kf[4][2], vf[4][2];
#pragma unroll
            for (int tf = 0; tf < 4; ++tf)
#pragma unroll
                for (int kc = 0; kc < 2; ++kc)
                    kf[tf][kc] = *(bf16x8*)(Kb + (16 * tf + m) * 128 +
                                            (((4 * kc + h) ^ (m & 7)) << 4));
#pragma unroll
            for (int nf = 0; nf < 4; ++nf)
#pragma unroll
                for (int kc = 0; kc < 2; ++kc)
                    vf[nf][kc] = *(bf16x8*)(Vb + (16 * nf + m) * 128 +
                                            (((4 * kc + h) ^ (m & 7)) << 4));

            // ---- QK^T swapped: lane holds q=m, t=16tf+4h+r ----
            f32x4 s[4];
            __builtin_amdgcn_s_setprio(1);
#pragma unroll
            for (int tf = 0; tf < 4; ++tf) {
                f32x4 z = {};
                z = __builtin_amdgcn_mfma_f32_16x16x32_bf16(kf[tf][0], aq[0], z, 0, 0, 0);
                z = __builtin_amdgcn_mfma_f32_16x16x32_bf16(kf[tf][1], aq[1], z, 0, 0, 0);
                s[tf] = z;
            }
            __builtin_amdgcn_s_setprio(0);

            if (it == nt - 1) {
#pragma unroll
                for (int tf = 0; tf < 4; ++tf)
#pragma unroll
                    for (int r = 0; r < 4; ++r) {
                        int gq = q0 + m;
                        int gt = t0 + tf * 16 + h * 4 + r;
                        if (gt > gq) s[tf][r] = -__builtin_inff();
                    }
            }

            // ---- online softmax (per-lane stats, defer-max) ----
            float mx = s[0][0];
#pragma unroll
            for (int tf = 0; tf < 4; ++tf)
#pragma unroll
                for (int r = 0; r < 4; ++r) mx = fmaxf(mx, s[tf][r]);
            mx = fmaxf(mx, __shfl_xor(mx, 16));
            mx = fmaxf(mx, __shfl_xor(mx, 32));
            if (!__all(mx <= mrow + 8.f)) {
                float mn = fmaxf(mrow, mx);
                float sf = __expf(mrow - mn);
                mrow = mn;
                lrow *= sf;
                float sfr[4];
#pragma unroll
                for (int r = 0; r < 4; ++r) sfr[r] = __shfl(sf, 20 * h + r);
#pragma unroll
                for (int nf = 0; nf < 4; ++nf)
#pragma unroll
                    for (int r = 0; r < 4; ++r) o[nf][r] *= sfr[r];
            }
            float rs = 0.f;
#pragma unroll
            for (int tf = 0; tf < 4; ++tf)
#pragma unroll
                for (int r = 0; r < 4; ++r) {
                    float pv = __expf(s[tf][r] - mrow);
                    s[tf][r] = pv;
                    rs += pv;
                }
            rs += __shfl_xor(rs, 16);
            rs += __shfl_xor(rs, 32);
            lrow += rs;

            // pack P -> wave-private LDS
#pragma unroll
            for (int tf = 0; tf < 4; ++tf)
#pragma unroll
                for (int rp = 0; rp < 2; ++rp) {
                    unsigned int w = ((unsigned int)bfbits(s[tf][2 * rp + 1]) << 16) |
                                     bfbits(s[tf][2 * rp]);
                    Pk[wid][m][(8 * tf + 2 * h + rp) ^ swz] = w;
                }

            // ---- PV ----
            __builtin_amdgcn_s_setprio(1);
#pragma unroll
            for (int kc = 0; kc < 2; ++kc) {
                bf16x8 ap = *(bf16x8*)&Pk[wid][m][(16 * kc + 4 * h) ^ swz];
#pragma unroll
                for (int nf = 0; nf < 4; ++nf)
                    o[nf] = __builtin_amdgcn_mfma_f32_16x16x32_bf16(
                        ap, vf[nf][kc], o[nf], 0, 0, 0);
            }
            __builtin_amdgcn_s_setprio(0);
        }
        __builtin_amdgcn_s_barrier();  // all reads of buf[cur] done; safe to overwrite
        cur ^= 1;
    }
#undef STAGE

    // ---- direct write-out (no merge: waves own distinct q-rows) ----
    const int b_ = bh >> 4, hh = bh & 15;
    float lcr[4];
#pragma unroll
    for (int r = 0; r < 4; ++r) lcr[r] = __shfl(lrow, 20 * h + r);
#pragma unroll
    for (int nf = 0; nf < 4; ++nf)
#pragma unroll
        for (int r = 0; r < 4; ++r) {
            float val = o[nf][r] / lcr[r];
            int s_ = q0 + h * 4 + r;
            AO[((size_t)(b_ * SEQ + s_)) * D_MODEL + hh * HEAD_DIM + nf * 16 + m] =
                (bf16)val;
        }
}

extern "C" void kernel_launch(void* const* d_in, const int* in_sizes, int n_in,
                              void* d_out, int out_size, void* d_ws, size_t ws_size,
                              hipStream_t stream) {
    const float* x  = (const float*)d_in[0];
    const float* Wq = (const float*)d_in[1];
    const float* bq = (const float*)d_in[2];
    const float* Wk = (const float*)d_in[3];
    const float* bk = (const float*)d_in[4];
    const float* Wv = (const float*)d_in[5];
    const float* bv = (const float*)d_in[6];
    const float* Wo = (const float*)d_in[7];
    const float* bo = (const float*)d_in[8];

    char* ws = (char*)d_ws;
    const size_t MB = 1u << 20;
    bf16* wt = (bf16*)ws;                  // 4 x [1024][1024] bf16 (QKV contiguous)
    bf16* xb = (bf16*)(ws + 8 * MB);       // [4096][1024] bf16
    bf16* Qb = (bf16*)(ws + 16 * MB);      // Q*0.125 [32][2048][64]; K; V^T [32][64][2048]
    bf16* AO = (bf16*)(ws + 40 * MB);      // [4096][1024] bf16

    const size_t WSTRIDE = (size_t)D_MODEL * D_MODEL;

    cvt_x<<<dim3(MROWS * D_MODEL / 4 / 256), dim3(256), 0, stream>>>(x, xb);
    cvt_wt<<<dim3(32, 32, 4), dim3(32, 32), 0, stream>>>(Wq, Wk, Wv, Wo, wt);

    gemm_k<0><<<dim3(24, 32), dim3(256), 0, stream>>>(xb, wt, bq, bk, bv, Qb);

    bf16* Kb = Qb + 4194304;
    bf16* VTb = Qb + 2 * 4194304;
    attn_k<<<dim3(1024), dim3(256), 0, stream>>>(Qb, Kb, VTb, AO);

    gemm_k<1><<<dim3(8, 32), dim3(256), 0, stream>>>(AO, wt + 3 * WSTRIDE, bo, bo, bo, d_out);
}

// Round 27
// 110.805 us; speedup vs baseline: 2.9840x; 1.0042x over previous
//
#include <hip/hip_runtime.h>
#include <hip/hip_bf16.h>
#include <cmath>

#define D_MODEL 1024
#define N_HEADS 16
#define HEAD_DIM 64
#define SEQ 2048
#define BATCH 2
#define MROWS (BATCH * SEQ)  // 4096

typedef __bf16 bf16;
typedef __bf16 bf16x8 __attribute__((ext_vector_type(8)));
typedef __bf16 bf16x4 __attribute__((ext_vector_type(4)));
typedef float f32x4 __attribute__((ext_vector_type(4)));

// GEMM LDS swizzle (64B rows): byte = row*64 + (cbyte ^ (((row>>1)&3)<<4))
#define SWZG(row, cbyte) ((row) * 64 + ((cbyte) ^ ((((row) >> 1) & 3) << 4)))

// async global->LDS, 16B per lane, linear dest (wave base + lane*16)
#define GLOAD16(g, l)                                                        \
    __builtin_amdgcn_global_load_lds(                                        \
        (const __attribute__((address_space(1))) void*)(g),                  \
        (__attribute__((address_space(3))) void*)(l), 16, 0, 0)

// native 2^x (v_exp_f32); __exp2f does not exist on ROCm device side
#define EXP2F(x) __builtin_amdgcn_exp2f(x)

static __device__ __forceinline__ unsigned short bfbits(float f) {
    bf16 b = (bf16)f;
    return *(unsigned short*)&b;
}

// ---------------- fp32 -> bf16 convert (x) ----------------
__global__ __launch_bounds__(256) void cvt_x(const float* __restrict__ x,
                                             bf16* __restrict__ xb) {
    int i = blockIdx.x * 256 + threadIdx.x;
    float4 v = ((const float4*)x)[i];
    bf16x4 o = { (bf16)v.x, (bf16)v.y, (bf16)v.z, (bf16)v.w };
    ((bf16x4*)xb)[i] = o;
}

// ---------------- weight transpose + convert: wt[z][n][k] = W_z[k][n] ----------------
__global__ void cvt_wt(const float* __restrict__ Wq, const float* __restrict__ Wk,
                       const float* __restrict__ Wv, const float* __restrict__ Wo,
                       bf16* __restrict__ wt) {
    __shared__ float tile[32][33];
    int z = blockIdx.z;
    const float* W = (z == 0) ? Wq : (z == 1) ? Wk : (z == 2) ? Wv : Wo;
    int n0 = blockIdx.x * 32, k0 = blockIdx.y * 32;
    int tx = threadIdx.x, ty = threadIdx.y;
    tile[ty][tx] = W[(size_t)(k0 + ty) * D_MODEL + n0 + tx];
    __syncthreads();
    wt[(size_t)z * D_MODEL * D_MODEL + (size_t)(n0 + ty) * D_MODEL + k0 + tx] =
        (bf16)tile[tx][ty];
}

// ---------------- GEMM: Y[M,N] = A[M,K] @ Wt[N,K]^T + bias (R21-proven) ----------------
// Triple-buffered LDS, 2-deep prefetch, counted vmcnt; MODE0 z==2 (V^T)
// epilogue via LDS transpose -> coalesced 256B stores.
// z==0 scale: 0.125 * log2(e) -> attn softmax runs in exp2 domain.
template <int MODE>
__global__ __launch_bounds__(256) void gemm_k(const bf16* __restrict__ A,
                                              const bf16* __restrict__ Bt,
                                              const float* __restrict__ b0,
                                              const float* __restrict__ b1,
                                              const float* __restrict__ b2,
                                              void* __restrict__ outp) {
    constexpr int BM = 128, BK = 32, KDIM = D_MODEL;
    __shared__ alignas(16) char SMEM[49152];  // As[3] + Bs[3]; reused as T
    char* Asb = SMEM;
    char* Bsb = SMEM + 24576;
    const int tid = threadIdx.x;
    const int wid = tid >> 6, lane = tid & 63;
    const int m0 = blockIdx.y * BM, n0 = blockIdx.x * BM;
    const int wr = (wid >> 1) * 64, wc = (wid & 1) * 64;
    f32x4 acc[4][4] = {};

#define GSTAGE(K0, BUF)                                                       \
    {                                                                         \
        _Pragma("unroll") for (int c = 0; c < 2; ++c) {                       \
            const int q = c * 4 + wid;                                        \
            const int row = q * 16 + (lane >> 2);                             \
            const int col = (lane & 3) ^ ((row >> 1) & 3);                    \
            GLOAD16(&A[(size_t)(m0 + row) * KDIM + (K0) + col * 8],           \
                    Asb + (BUF) * 8192 + q * 1024);                           \
            GLOAD16(&Bt[(size_t)(n0 + row) * KDIM + (K0) + col * 8],          \
                    Bsb + (BUF) * 8192 + q * 1024);                           \
        }                                                                     \
    }

    GSTAGE(0, 0);
    GSTAGE(BK, 1);
    int cur = 0;
    for (int k0 = 0; k0 < KDIM; k0 += BK) {
        if (k0 + 2 * BK < KDIM) {
            int nb = cur + 2;
            if (nb >= 3) nb -= 3;
            GSTAGE(k0 + 2 * BK, nb);
            asm volatile("s_waitcnt vmcnt(8)" ::: "memory");
        } else if (k0 + BK < KDIM) {
            asm volatile("s_waitcnt vmcnt(4)" ::: "memory");
        } else {
            asm volatile("s_waitcnt vmcnt(0)" ::: "memory");
        }
        __builtin_amdgcn_s_barrier();

        char* Ab = Asb + cur * 8192;
        char* Bb = Bsb + cur * 8192;
        const int cb = (lane >> 4) * 16;
        bf16x8 a[4], b[4];
#pragma unroll
        for (int m = 0; m < 4; ++m) {
            int r = wr + m * 16 + (lane & 15);
            a[m] = *(bf16x8*)(Ab + SWZG(r, cb));
        }
#pragma unroll
        for (int n = 0; n < 4; ++n) {
            int r = wc + n * 16 + (lane & 15);
            b[n] = *(bf16x8*)(Bb + SWZG(r, cb));
        }
#pragma unroll
        for (int m = 0; m < 4; ++m)
#pragma unroll
            for (int n = 0; n < 4; ++n)
                acc[m][n] = __builtin_amdgcn_mfma_f32_16x16x32_bf16(a[m], b[n], acc[m][n], 0, 0, 0);

        __builtin_amdgcn_s_barrier();
        cur = (cur == 2) ? 0 : cur + 1;
    }
#undef GSTAGE

    const int z = n0 >> 10;
    const float* bias = (MODE == 1) ? b0 : ((z == 0) ? b0 : (z == 1) ? b1 : b2);

    if (MODE == 0 && z == 2) {
        // V^T epilogue via LDS transpose: coalesced 256B stores
        bf16* T = (bf16*)SMEM;
#pragma unroll
        for (int m = 0; m < 4; ++m)
#pragma unroll
            for (int n = 0; n < 4; ++n)
#pragma unroll
                for (int r = 0; r < 4; ++r) {
                    int ml = wr + m * 16 + (lane >> 4) * 4 + r;
                    int nl = wc + n * 16 + (lane & 15);
                    float val = acc[m][n][r] + bias[(n0 & 1023) + nl];
                    *(bf16*)((char*)T + nl * 256 + ((2 * ml) ^ ((nl & 7) << 4))) = (bf16)val;
                }
        __builtin_amdgcn_s_barrier();
        const int b_ = m0 >> 11;
        const int s_base = m0 & 2047;
#pragma unroll
        for (int c = 0; c < 8; ++c) {
            int idx = c * 256 + tid;
            int nl = idx >> 4, j = idx & 15;
            bf16x8 v = *(bf16x8*)((char*)T + nl * 256 + ((16 * j) ^ ((nl & 7) << 4)));
            int colN = (n0 & 1023) + nl;
            int head = colN >> 6, hd = colN & 63;
            *(bf16x8*)&((bf16*)outp)[(size_t)2 * 4194304 +
                                     ((size_t)(b_ * N_HEADS + head) * HEAD_DIM + hd) * SEQ +
                                     s_base + 8 * j] = v;
        }
        return;
    }

#pragma unroll
    for (int m = 0; m < 4; ++m)
#pragma unroll
        for (int n = 0; n < 4; ++n)
#pragma unroll
            for (int r = 0; r < 4; ++r) {
                int grow = m0 + wr + m * 16 + (lane >> 4) * 4 + r;
                int gcol = n0 + wc + n * 16 + (lane & 15);
                if (MODE == 0) {
                    int colN = gcol & 1023;
                    float val = acc[m][n][r] + bias[colN];
                    if (z == 0) val *= 0.18033688011112042f;  // 0.125 * log2(e): exp2 domain
                    int b_ = grow >> 11, s_ = grow & 2047;
                    int h = colN >> 6, hd = colN & 63;
                    ((bf16*)outp)[(size_t)z * 4194304 +
                                  ((size_t)(b_ * N_HEADS + h) * SEQ + s_) * HEAD_DIM + hd] =
                        (bf16)val;
                } else {
                    float val = acc[m][n][r] + bias[gcol];
                    ((float*)outp)[(size_t)grow * D_MODEL + gcol] = val;
                }
            }
}

// ---------------- flash attention: 64-row half-bands (R25) + exp2 softmax ----------------
// grid 1024 x 256 threads (4 waves x 16 rows = 64-row half-band hb in 0..31).
// Quarter-interleaved hb order (constant per-CU work, heavy-first LPT).
// Scores arrive pre-scaled by 0.125*log2e -> softmax uses native v_exp_f32
// (2^x) with no per-value mul; defer-max threshold 8*log2e = 11.5416 (same
// e^8 bound). Max and sum reductions are explicit depth-4 trees.
__global__ __launch_bounds__(256) void attn_k(const bf16* __restrict__ Qg,
                                              const bf16* __restrict__ Kg,
                                              const bf16* __restrict__ VTg,
                                              bf16* __restrict__ AO) {
    __shared__ alignas(16) bf16 Ks[2][64 * 64];         // 16 KB
    __shared__ alignas(16) bf16 Vs[2][64 * 64];         // 16 KB
    __shared__ alignas(16) unsigned int Pk[4][16][32];  // 8 KB
    const int tid = threadIdx.x, wid = tid >> 6, lane = tid & 63;
    const int m = lane & 15, h = lane >> 4;
    const int idx = blockIdx.x;
    const int bh = idx & 31;                // bh%8 fixes XCD -> KV L2 locality
    const int a = (idx >> 5) & 7;
    const int qd = idx >> 8;
    const int hb = (qd == 0) ? (31 - a) : (qd == 1) ? (23 - a) : (qd == 2) ? (8 + a) : a;
    const int q0 = hb * 64 + wid * 16;
    const size_t base = (size_t)bh * SEQ * HEAD_DIM;
    const bf16* VT = VTg + (size_t)bh * HEAD_DIM * SEQ;
    const int swz = (m & 7) << 2;
    const int nt = hb + 1;  // same for all waves in the block

    bf16x8 aq[2];
#pragma unroll
    for (int kc = 0; kc < 2; ++kc)
        aq[kc] = *(const bf16x8*)
            &Qg[base + (size_t)(q0 + m) * HEAD_DIM + kc * 32 + h * 8];

    f32x4 o[4] = {};
    float mrow = -__builtin_inff();
    float lrow = 0.f;

    // stage tile T0 into buffer BUF: 2 K + 2 V GLOAD16 per thread (256 threads).
#define STAGE(T0, BUF)                                                            \
    {                                                                             \
        _Pragma("unroll") for (int c = 0; c < 2; ++c) {                           \
            int chunk = c * 256 + tid;                                            \
            int row = chunk >> 3, sl = chunk & 7;                                 \
            GLOAD16(&Kg[base + (size_t)((T0) + row) * HEAD_DIM +                  \
                        8 * (sl ^ (row & 7))],                                    \
                    (char*)&Ks[BUF][0] + chunk * 16);                             \
            GLOAD16(&VT[(size_t)row * SEQ + (T0) + 8 * (sl ^ (row & 7))],         \
                    (char*)&Vs[BUF][0] + chunk * 16);                             \
        }                                                                         \
    }

    STAGE(0, 0);
    int cur = 0;
    for (int it = 0; it < nt; ++it) {
        if (it + 1 < nt) {
            STAGE((it + 1) * 64, cur ^ 1);
            asm volatile("s_waitcnt vmcnt(4)" ::: "memory");  // current tile landed
        } else {
            asm volatile("s_waitcnt vmcnt(0)" ::: "memory");
        }
        __builtin_amdgcn_s_barrier();  // all waves' stage of tile it complete

        {
            const int t0 = it * 64;
            char* Kb = (char*)&Ks[cur][0];
            char* Vb = (char*)&Vs[cur][0];
            bf16x8 kf[4][2], vf[4][2];
#pragma unroll
            for (int tf = 0; tf < 4; ++tf)
#pragma unroll
                for (int kc = 0; kc < 2; ++kc)
                    kf[tf][kc] = *(bf16x8*)(Kb + (16 * tf + m) * 128 +
                                            (((4 * kc + h) ^ (m & 7)) << 4));
#pragma unroll
            for (int nf = 0; nf < 4; ++nf)
#pragma unroll
                for (int kc = 0; kc < 2; ++kc)
                    vf[nf][kc] = *(bf16x8*)(Vb + (16 * nf + m) * 128 +
                                            (((4 * kc + h) ^ (m & 7)) << 4));

            // ---- QK^T swapped: lane holds q=m, t=16tf+4h+r (exp2-domain scores) ----
            f32x4 s[4];
            __builtin_amdgcn_s_setprio(1);
#pragma unroll
            for (int tf = 0; tf < 4; ++tf) {
                f32x4 z = {};
                z = __builtin_amdgcn_mfma_f32_16x16x32_bf16(kf[tf][0], aq[0], z, 0, 0, 0);
                z = __builtin_amdgcn_mfma_f32_16x16x32_bf16(kf[tf][1], aq[1], z, 0, 0, 0);
                s[tf] = z;
            }
            __builtin_amdgcn_s_setprio(0);

            if (it == nt - 1) {
#pragma unroll
                for (int tf = 0; tf < 4; ++tf)
#pragma unroll
                    for (int r = 0; r < 4; ++r) {
                        int gq = q0 + m;
                        int gt = t0 + tf * 16 + h * 4 + r;
                        if (gt > gq) s[tf][r] = -__builtin_inff();
                    }
            }

            // ---- online softmax in exp2 domain (tree reductions, defer-max) ----
            float mt[4];
#pragma unroll
            for (int tf = 0; tf < 4; ++tf)
                mt[tf] = fmaxf(fmaxf(s[tf][0], s[tf][1]), fmaxf(s[tf][2], s[tf][3]));
            float mx = fmaxf(fmaxf(mt[0], mt[1]), fmaxf(mt[2], mt[3]));
            mx = fmaxf(mx, __shfl_xor(mx, 16));
            mx = fmaxf(mx, __shfl_xor(mx, 32));
            if (!__all(mx <= mrow + 11.541560327f)) {  // 8*log2(e)
                float mn = fmaxf(mrow, mx);
                float sf = EXP2F(mrow - mn);
                mrow = mn;
                lrow *= sf;
                float sfr[4];
#pragma unroll
                for (int r = 0; r < 4; ++r) sfr[r] = __shfl(sf, 20 * h + r);
#pragma unroll
                for (int nf = 0; nf < 4; ++nf)
#pragma unroll
                    for (int r = 0; r < 4; ++r) o[nf][r] *= sfr[r];
            }
            float rt[4];
#pragma unroll
            for (int tf = 0; tf < 4; ++tf) {
#pragma unroll
                for (int r = 0; r < 4; ++r) s[tf][r] = EXP2F(s[tf][r] - mrow);
                rt[tf] = (s[tf][0] + s[tf][1]) + (s[tf][2] + s[tf][3]);
            }
            float rs = (rt[0] + rt[1]) + (rt[2] + rt[3]);
            rs += __shfl_xor(rs, 16);
            rs += __shfl_xor(rs, 32);
            lrow += rs;

            // pack P -> wave-private LDS
#pragma unroll
            for (int tf = 0; tf < 4; ++tf)
#pragma unroll
                for (int rp = 0; rp < 2; ++rp) {
                    unsigned int w = ((unsigned int)bfbits(s[tf][2 * rp + 1]) << 16) |
                                     bfbits(s[tf][2 * rp]);
                    Pk[wid][m][(8 * tf + 2 * h + rp) ^ swz] = w;
                }

            // ---- PV ----
            __builtin_amdgcn_s_setprio(1);
#pragma unroll
            for (int kc = 0; kc < 2; ++kc) {
                bf16x8 ap = *(bf16x8*)&Pk[wid][m][(16 * kc + 4 * h) ^ swz];
#pragma unroll
                for (int nf = 0; nf < 4; ++nf)
                    o[nf] = __builtin_amdgcn_mfma_f32_16x16x32_bf16(
                        ap, vf[nf][kc], o[nf], 0, 0, 0);
            }
            __builtin_amdgcn_s_setprio(0);
        }
        __builtin_amdgcn_s_barrier();  // all reads of buf[cur] done; safe to overwrite
        cur ^= 1;
    }
#undef STAGE

    // ---- direct write-out (no merge: waves own distinct q-rows) ----
    const int b_ = bh >> 4, hh = bh & 15;
    float lcr[4];
#pragma unroll
    for (int r = 0; r < 4; ++r) lcr[r] = __shfl(lrow, 20 * h + r);
#pragma unroll
    for (int nf = 0; nf < 4; ++nf)
#pragma unroll
        for (int r = 0; r < 4; ++r) {
            float val = o[nf][r] / lcr[r];
            int s_ = q0 + h * 4 + r;
            AO[((size_t)(b_ * SEQ + s_)) * D_MODEL + hh * HEAD_DIM + nf * 16 + m] =
                (bf16)val;
        }
}

extern "C" void kernel_launch(void* const* d_in, const int* in_sizes, int n_in,
                              void* d_out, int out_size, void* d_ws, size_t ws_size,
                              hipStream_t stream) {
    const float* x  = (const float*)d_in[0];
    const float* Wq = (const float*)d_in[1];
    const float* bq = (const float*)d_in[2];
    const float* Wk = (const float*)d_in[3];
    const float* bk = (const float*)d_in[4];
    const float* Wv = (const float*)d_in[5];
    const float* bv = (const float*)d_in[6];
    const float* Wo = (const float*)d_in[7];
    const float* bo = (const float*)d_in[8];

    char* ws = (char*)d_ws;
    const size_t MB = 1u << 20;
    bf16* wt = (bf16*)ws;                  // 4 x [1024][1024] bf16 (QKV contiguous)
    bf16* xb = (bf16*)(ws + 8 * MB);       // [4096][1024] bf16
    bf16* Qb = (bf16*)(ws + 16 * MB);      // Q*0.125*log2e [32][2048][64]; K; V^T [32][64][2048]
    bf16* AO = (bf16*)(ws + 40 * MB);      // [4096][1024] bf16

    const size_t WSTRIDE = (size_t)D_MODEL * D_MODEL;

    cvt_x<<<dim3(MROWS * D_MODEL / 4 / 256), dim3(256), 0, stream>>>(x, xb);
    cvt_wt<<<dim3(32, 32, 4), dim3(32, 32), 0, stream>>>(Wq, Wk, Wv, Wo, wt);

    gemm_k<0><<<dim3(24, 32), dim3(256), 0, stream>>>(xb, wt, bq, bk, bv, Qb);

    bf16* Kb = Qb + 4194304;
    bf16* VTb = Qb + 2 * 4194304;
    attn_k<<<dim3(1024), dim3(256), 0, stream>>>(Qb, Kb, VTb, AO);

    gemm_k<1><<<dim3(8, 32), dim3(256), 0, stream>>>(AO, wt + 3 * WSTRIDE, bo, bo, bo, d_out);
}

// Round 28
// 108.228 us; speedup vs baseline: 3.0551x; 1.0238x over previous
//
#include <hip/hip_runtime.h>
#include <hip/hip_bf16.h>
#include <cmath>

#define D_MODEL 1024
#define N_HEADS 16
#define HEAD_DIM 64
#define SEQ 2048
#define BATCH 2
#define MROWS (BATCH * SEQ)  // 4096

typedef __bf16 bf16;
typedef __bf16 bf16x8 __attribute__((ext_vector_type(8)));
typedef __bf16 bf16x4 __attribute__((ext_vector_type(4)));
typedef float f32x4 __attribute__((ext_vector_type(4)));

// GEMM LDS swizzle (64B rows): byte = row*64 + (cbyte ^ (((row>>1)&3)<<4))
#define SWZG(row, cbyte) ((row) * 64 + ((cbyte) ^ ((((row) >> 1) & 3) << 4)))

// async global->LDS, 16B per lane, linear dest (wave base + lane*16)
#define GLOAD16(g, l)                                                        \
    __builtin_amdgcn_global_load_lds(                                        \
        (const __attribute__((address_space(1))) void*)(g),                  \
        (__attribute__((address_space(3))) void*)(l), 16, 0, 0)

// native 2^x (v_exp_f32); __exp2f does not exist on ROCm device side
#define EXP2F(x) __builtin_amdgcn_exp2f(x)

static __device__ __forceinline__ unsigned short bfbits(float f) {
    bf16 b = (bf16)f;
    return *(unsigned short*)&b;
}

// ---------------- fp32 -> bf16 convert (x) ----------------
__global__ __launch_bounds__(256) void cvt_x(const float* __restrict__ x,
                                             bf16* __restrict__ xb) {
    int i = blockIdx.x * 256 + threadIdx.x;
    float4 v = ((const float4*)x)[i];
    bf16x4 o = { (bf16)v.x, (bf16)v.y, (bf16)v.z, (bf16)v.w };
    ((bf16x4*)xb)[i] = o;
}

// ---------------- weight transpose + convert: wt[z][n][k] = W_z[k][n] ----------------
__global__ void cvt_wt(const float* __restrict__ Wq, const float* __restrict__ Wk,
                       const float* __restrict__ Wv, const float* __restrict__ Wo,
                       bf16* __restrict__ wt) {
    __shared__ float tile[32][33];
    int z = blockIdx.z;
    const float* W = (z == 0) ? Wq : (z == 1) ? Wk : (z == 2) ? Wv : Wo;
    int n0 = blockIdx.x * 32, k0 = blockIdx.y * 32;
    int tx = threadIdx.x, ty = threadIdx.y;
    tile[ty][tx] = W[(size_t)(k0 + ty) * D_MODEL + n0 + tx];
    __syncthreads();
    wt[(size_t)z * D_MODEL * D_MODEL + (size_t)(n0 + ty) * D_MODEL + k0 + tx] =
        (bf16)tile[tx][ty];
}

// ---------------- GEMM: Y[M,N] = A[M,K] @ Wt[N,K]^T + bias ----------------
// 512 threads / 8 waves, each wave owns a 32x64 sub-tile (acc 2x4): same tiles
// and staging traffic as the 4-wave version but 24 waves/CU (R18 playbook:
// double TLP at constant traffic). Triple-buffered LDS, 2-deep prefetch,
// counted vmcnt (2 loads/stage -> 4/2/0). MODE0 z==2 (V^T) epilogue via LDS
// transpose -> coalesced 256B stores. z==0 scale: 0.125*log2e (exp2 domain).
template <int MODE>
__global__ __launch_bounds__(512) void gemm_k(const bf16* __restrict__ A,
                                              const bf16* __restrict__ Bt,
                                              const float* __restrict__ b0,
                                              const float* __restrict__ b1,
                                              const float* __restrict__ b2,
                                              void* __restrict__ outp) {
    constexpr int BM = 128, BK = 32, KDIM = D_MODEL;
    __shared__ alignas(16) char SMEM[49152];  // As[3] + Bs[3]; reused as T
    char* Asb = SMEM;
    char* Bsb = SMEM + 24576;
    const int tid = threadIdx.x;
    const int wid = tid >> 6, lane = tid & 63;
    const int m0 = blockIdx.y * BM, n0 = blockIdx.x * BM;
    const int wr = (wid >> 1) * 32, wc = (wid & 1) * 64;
    const int ml = lane & 15;
    f32x4 acc[2][4] = {};

    // stage one K-tile into buffer BUF: 1 A + 1 B GLOAD16 per thread (512 thr).
#define GSTAGE(K0, BUF)                                                       \
    {                                                                         \
        const int row = tid >> 2;                                             \
        const int col = (tid & 3) ^ ((row >> 1) & 3);                         \
        GLOAD16(&A[(size_t)(m0 + row) * KDIM + (K0) + col * 8],               \
                Asb + (BUF) * 8192 + tid * 16);                               \
        GLOAD16(&Bt[(size_t)(n0 + row) * KDIM + (K0) + col * 8],              \
                Bsb + (BUF) * 8192 + tid * 16);                               \
    }

    GSTAGE(0, 0);
    GSTAGE(BK, 1);
    int cur = 0;
    for (int k0 = 0; k0 < KDIM; k0 += BK) {
        if (k0 + 2 * BK < KDIM) {
            int nb = cur + 2;
            if (nb >= 3) nb -= 3;
            GSTAGE(k0 + 2 * BK, nb);
            asm volatile("s_waitcnt vmcnt(4)" ::: "memory");  // tile k0 landed
        } else if (k0 + BK < KDIM) {
            asm volatile("s_waitcnt vmcnt(2)" ::: "memory");
        } else {
            asm volatile("s_waitcnt vmcnt(0)" ::: "memory");
        }
        __builtin_amdgcn_s_barrier();

        char* Ab = Asb + cur * 8192;
        char* Bb = Bsb + cur * 8192;
        const int cb = (lane >> 4) * 16;
        bf16x8 a[2], b[4];
#pragma unroll
        for (int m = 0; m < 2; ++m) {
            int r = wr + m * 16 + ml;
            a[m] = *(bf16x8*)(Ab + SWZG(r, cb));
        }
#pragma unroll
        for (int n = 0; n < 4; ++n) {
            int r = wc + n * 16 + ml;
            b[n] = *(bf16x8*)(Bb + SWZG(r, cb));
        }
#pragma unroll
        for (int m = 0; m < 2; ++m)
#pragma unroll
            for (int n = 0; n < 4; ++n)
                acc[m][n] = __builtin_amdgcn_mfma_f32_16x16x32_bf16(a[m], b[n], acc[m][n], 0, 0, 0);

        __builtin_amdgcn_s_barrier();
        cur = (cur == 2) ? 0 : cur + 1;
    }
#undef GSTAGE

    const int z = n0 >> 10;
    const float* bias = (MODE == 1) ? b0 : ((z == 0) ? b0 : (z == 1) ? b1 : b2);

    if (MODE == 0 && z == 2) {
        // V^T epilogue via LDS transpose: coalesced 256B stores
        bf16* T = (bf16*)SMEM;  // [128 nl][128 ml] bf16, swizzled rows (32 KB)
#pragma unroll
        for (int m = 0; m < 2; ++m)
#pragma unroll
            for (int n = 0; n < 4; ++n)
#pragma unroll
                for (int r = 0; r < 4; ++r) {
                    int mll = wr + m * 16 + (lane >> 4) * 4 + r;
                    int nl = wc + n * 16 + ml;
                    float val = acc[m][n][r] + bias[(n0 & 1023) + nl];
                    *(bf16*)((char*)T + nl * 256 + ((2 * mll) ^ ((nl & 7) << 4))) = (bf16)val;
                }
        __builtin_amdgcn_s_barrier();
        const int b_ = m0 >> 11;
        const int s_base = m0 & 2047;
#pragma unroll
        for (int c = 0; c < 4; ++c) {
            int idx = c * 512 + tid;           // 0..2047 = nl(128) x j(16)
            int nl = idx >> 4, j = idx & 15;
            bf16x8 v = *(bf16x8*)((char*)T + nl * 256 + ((16 * j) ^ ((nl & 7) << 4)));
            int colN = (n0 & 1023) + nl;
            int head = colN >> 6, hd = colN & 63;
            *(bf16x8*)&((bf16*)outp)[(size_t)2 * 4194304 +
                                     ((size_t)(b_ * N_HEADS + head) * HEAD_DIM + hd) * SEQ +
                                     s_base + 8 * j] = v;
        }
        return;
    }

#pragma unroll
    for (int m = 0; m < 2; ++m)
#pragma unroll
        for (int n = 0; n < 4; ++n)
#pragma unroll
            for (int r = 0; r < 4; ++r) {
                int grow = m0 + wr + m * 16 + (lane >> 4) * 4 + r;
                int gcol = n0 + wc + n * 16 + ml;
                if (MODE == 0) {
                    int colN = gcol & 1023;
                    float val = acc[m][n][r] + bias[colN];
                    if (z == 0) val *= 0.18033688011112042f;  // 0.125*log2e: exp2 domain
                    int b_ = grow >> 11, s_ = grow & 2047;
                    int h = colN >> 6, hd = colN & 63;
                    ((bf16*)outp)[(size_t)z * 4194304 +
                                  ((size_t)(b_ * N_HEADS + h) * SEQ + s_) * HEAD_DIM + hd] =
                        (bf16)val;
                } else {
                    float val = acc[m][n][r] + bias[gcol];
                    ((float*)outp)[(size_t)grow * D_MODEL + gcol] = val;
                }
            }
}

// ---------------- flash attention: 64-row half-bands + exp2 softmax (R27, 54.3us) ----------------
__global__ __launch_bounds__(256) void attn_k(const bf16* __restrict__ Qg,
                                              const bf16* __restrict__ Kg,
                                              const bf16* __restrict__ VTg,
                                              bf16* __restrict__ AO) {
    __shared__ alignas(16) bf16 Ks[2][64 * 64];         // 16 KB
    __shared__ alignas(16) bf16 Vs[2][64 * 64];         // 16 KB
    __shared__ alignas(16) unsigned int Pk[4][16][32];  // 8 KB
    const int tid = threadIdx.x, wid = tid >> 6, lane = tid & 63;
    const int m = lane & 15, h = lane >> 4;
    const int idx = blockIdx.x;
    const int bh = idx & 31;                // bh%8 fixes XCD -> KV L2 locality
    const int a = (idx >> 5) & 7;
    const int qd = idx >> 8;
    const int hb = (qd == 0) ? (31 - a) : (qd == 1) ? (23 - a) : (qd == 2) ? (8 + a) : a;
    const int q0 = hb * 64 + wid * 16;
    const size_t base = (size_t)bh * SEQ * HEAD_DIM;
    const bf16* VT = VTg + (size_t)bh * HEAD_DIM * SEQ;
    const int swz = (m & 7) << 2;
    const int nt = hb + 1;  // same for all waves in the block

    bf16x8 aq[2];
#pragma unroll
    for (int kc = 0; kc < 2; ++kc)
        aq[kc] = *(const bf16x8*)
            &Qg[base + (size_t)(q0 + m) * HEAD_DIM + kc * 32 + h * 8];

    f32x4 o[4] = {};
    float mrow = -__builtin_inff();
    float lrow = 0.f;

#define STAGE(T0, BUF)                                                            \
    {                                                                             \
        _Pragma("unroll") for (int c = 0; c < 2; ++c) {                           \
            int chunk = c * 256 + tid;                                            \
            int row = chunk >> 3, sl = chunk & 7;                                 \
            GLOAD16(&Kg[base + (size_t)((T0) + row) * HEAD_DIM +                  \
                        8 * (sl ^ (row & 7))],                                    \
                    (char*)&Ks[BUF][0] + chunk * 16);                             \
            GLOAD16(&VT[(size_t)row * SEQ + (T0) + 8 * (sl ^ (row & 7))],         \
                    (char*)&Vs[BUF][0] + chunk * 16);                             \
        }                                                                         \
    }

    STAGE(0, 0);
    int cur = 0;
    for (int it = 0; it < nt; ++it) {
        if (it + 1 < nt) {
            STAGE((it + 1) * 64, cur ^ 1);
            asm volatile("s_waitcnt vmcnt(4)" ::: "memory");  // current tile landed
        } else {
            asm volatile("s_waitcnt vmcnt(0)" ::: "memory");
        }
        __builtin_amdgcn_s_barrier();  // all waves' stage of tile it complete

        {
            const int t0 = it * 64;
            char* Kb = (char*)&Ks[cur][0];
            char* Vb = (char*)&Vs[cur][0];
            bf16x8 kf[4][2], vf[4][2];
#pragma unroll
            for (int tf = 0; tf < 4; ++tf)
#pragma unroll
                for (int kc = 0; kc < 2; ++kc)
                    kf[tf][kc] = *(bf16x8*)(Kb + (16 * tf + m) * 128 +
                                            (((4 * kc + h) ^ (m & 7)) << 4));
#pragma unroll
            for (int nf = 0; nf < 4; ++nf)
#pragma unroll
                for (int kc = 0; kc < 2; ++kc)
                    vf[nf][kc] = *(bf16x8*)(Vb + (16 * nf + m) * 128 +
                                            (((4 * kc + h) ^ (m & 7)) << 4));

            // ---- QK^T swapped: lane holds q=m, t=16tf+4h+r (exp2-domain scores) ----
            f32x4 s[4];
            __builtin_amdgcn_s_setprio(1);
#pragma unroll
            for (int tf = 0; tf < 4; ++tf) {
                f32x4 z = {};
                z = __builtin_amdgcn_mfma_f32_16x16x32_bf16(kf[tf][0], aq[0], z, 0, 0, 0);
                z = __builtin_amdgcn_mfma_f32_16x16x32_bf16(kf[tf][1], aq[1], z, 0, 0, 0);
                s[tf] = z;
            }
            __builtin_amdgcn_s_setprio(0);

            if (it == nt - 1) {
#pragma unroll
                for (int tf = 0; tf < 4; ++tf)
#pragma unroll
                    for (int r = 0; r < 4; ++r) {
                        int gq = q0 + m;
                        int gt = t0 + tf * 16 + h * 4 + r;
                        if (gt > gq) s[tf][r] = -__builtin_inff();
                    }
            }

            // ---- online softmax in exp2 domain (tree reductions, defer-max) ----
            float mt[4];
#pragma unroll
            for (int tf = 0; tf < 4; ++tf)
                mt[tf] = fmaxf(fmaxf(s[tf][0], s[tf][1]), fmaxf(s[tf][2], s[tf][3]));
            float mx = fmaxf(fmaxf(mt[0], mt[1]), fmaxf(mt[2], mt[3]));
            mx = fmaxf(mx, __shfl_xor(mx, 16));
            mx = fmaxf(mx, __shfl_xor(mx, 32));
            if (!__all(mx <= mrow + 11.541560327f)) {  // 8*log2(e)
                float mn = fmaxf(mrow, mx);
                float sf = EXP2F(mrow - mn);
                mrow = mn;
                lrow *= sf;
                float sfr[4];
#pragma unroll
                for (int r = 0; r < 4; ++r) sfr[r] = __shfl(sf, 20 * h + r);
#pragma unroll
                for (int nf = 0; nf < 4; ++nf)
#pragma unroll
                    for (int r = 0; r < 4; ++r) o[nf][r] *= sfr[r];
            }
            float rt[4];
#pragma unroll
            for (int tf = 0; tf < 4; ++tf) {
#pragma unroll
                for (int r = 0; r < 4; ++r) s[tf][r] = EXP2F(s[tf][r] - mrow);
                rt[tf] = (s[tf][0] + s[tf][1]) + (s[tf][2] + s[tf][3]);
            }
            float rs = (rt[0] + rt[1]) + (rt[2] + rt[3]);
            rs += __shfl_xor(rs, 16);
            rs += __shfl_xor(rs, 32);
            lrow += rs;

            // pack P -> wave-private LDS
#pragma unroll
            for (int tf = 0; tf < 4; ++tf)
#pragma unroll
                for (int rp = 0; rp < 2; ++rp) {
                    unsigned int w = ((unsigned int)bfbits(s[tf][2 * rp + 1]) << 16) |
                                     bfbits(s[tf][2 * rp]);
                    Pk[wid][m][(8 * tf + 2 * h + rp) ^ swz] = w;
                }

            // ---- PV ----
            __builtin_amdgcn_s_setprio(1);
#pragma unroll
            for (int kc = 0; kc < 2; ++kc) {
                bf16x8 ap = *(bf16x8*)&Pk[wid][m][(16 * kc + 4 * h) ^ swz];
#pragma unroll
                for (int nf = 0; nf < 4; ++nf)
                    o[nf] = __builtin_amdgcn_mfma_f32_16x16x32_bf16(
                        ap, vf[nf][kc], o[nf], 0, 0, 0);
            }
            __builtin_amdgcn_s_setprio(0);
        }
        __builtin_amdgcn_s_barrier();  // all reads of buf[cur] done; safe to overwrite
        cur ^= 1;
    }
#undef STAGE

    // ---- direct write-out (no merge: waves own distinct q-rows) ----
    const int b_ = bh >> 4, hh = bh & 15;
    float lcr[4];
#pragma unroll
    for (int r = 0; r < 4; ++r) lcr[r] = __shfl(lrow, 20 * h + r);
#pragma unroll
    for (int nf = 0; nf < 4; ++nf)
#pragma unroll
        for (int r = 0; r < 4; ++r) {
            float val = o[nf][r] / lcr[r];
            int s_ = q0 + h * 4 + r;
            AO[((size_t)(b_ * SEQ + s_)) * D_MODEL + hh * HEAD_DIM + nf * 16 + m] =
                (bf16)val;
        }
}

extern "C" void kernel_launch(void* const* d_in, const int* in_sizes, int n_in,
                              void* d_out, int out_size, void* d_ws, size_t ws_size,
                              hipStream_t stream) {
    const float* x  = (const float*)d_in[0];
    const float* Wq = (const float*)d_in[1];
    const float* bq = (const float*)d_in[2];
    const float* Wk = (const float*)d_in[3];
    const float* bk = (const float*)d_in[4];
    const float* Wv = (const float*)d_in[5];
    const float* bv = (const float*)d_in[6];
    const float* Wo = (const float*)d_in[7];
    const float* bo = (const float*)d_in[8];

    char* ws = (char*)d_ws;
    const size_t MB = 1u << 20;
    bf16* wt = (bf16*)ws;                  // 4 x [1024][1024] bf16 (QKV contiguous)
    bf16* xb = (bf16*)(ws + 8 * MB);       // [4096][1024] bf16
    bf16* Qb = (bf16*)(ws + 16 * MB);      // Q*0.125*log2e [32][2048][64]; K; V^T [32][64][2048]
    bf16* AO = (bf16*)(ws + 40 * MB);      // [4096][1024] bf16

    const size_t WSTRIDE = (size_t)D_MODEL * D_MODEL;

    cvt_x<<<dim3(MROWS * D_MODEL / 4 / 256), dim3(256), 0, stream>>>(x, xb);
    cvt_wt<<<dim3(32, 32, 4), dim3(32, 32), 0, stream>>>(Wq, Wk, Wv, Wo, wt);

    gemm_k<0><<<dim3(24, 32), dim3(512), 0, stream>>>(xb, wt, bq, bk, bv, Qb);

    bf16* Kb = Qb + 4194304;
    bf16* VTb = Qb + 2 * 4194304;
    attn_k<<<dim3(1024), dim3(256), 0, stream>>>(Qb, Kb, VTb, AO);

    gemm_k<1><<<dim3(8, 32), dim3(512), 0, stream>>>(AO, wt + 3 * WSTRIDE, bo, bo, bo, d_out);
}

// Round 29
// 100.794 us; speedup vs baseline: 3.2804x; 1.0738x over previous
//
#include <hip/hip_runtime.h>
#include <hip/hip_bf16.h>
#include <cmath>

#define D_MODEL 1024
#define N_HEADS 16
#define HEAD_DIM 64
#define SEQ 2048
#define BATCH 2
#define MROWS (BATCH * SEQ)  // 4096

typedef __bf16 bf16;
typedef __bf16 bf16x8 __attribute__((ext_vector_type(8)));
typedef __bf16 bf16x4 __attribute__((ext_vector_type(4)));
typedef float f32x4 __attribute__((ext_vector_type(4)));

// async global->LDS, 16B per lane, linear dest (wave base + lane*16)
#define GLOAD16(g, l)                                                        \
    __builtin_amdgcn_global_load_lds(                                        \
        (const __attribute__((address_space(1))) void*)(g),                  \
        (__attribute__((address_space(3))) void*)(l), 16, 0, 0)

// native 2^x (v_exp_f32); __exp2f does not exist on ROCm device side
#define EXP2F(x) __builtin_amdgcn_exp2f(x)

static __device__ __forceinline__ unsigned short bfbits(float f) {
    bf16 b = (bf16)f;
    return *(unsigned short*)&b;
}

// ---------------- fp32 -> bf16 convert (x) ----------------
__global__ __launch_bounds__(256) void cvt_x(const float* __restrict__ x,
                                             bf16* __restrict__ xb) {
    int i = blockIdx.x * 256 + threadIdx.x;
    float4 v = ((const float4*)x)[i];
    bf16x4 o = { (bf16)v.x, (bf16)v.y, (bf16)v.z, (bf16)v.w };
    ((bf16x4*)xb)[i] = o;
}

// ---------------- weight transpose + convert: wt[z][n][k] = W_z[k][n] ----------------
__global__ void cvt_wt(const float* __restrict__ Wq, const float* __restrict__ Wk,
                       const float* __restrict__ Wv, const float* __restrict__ Wo,
                       bf16* __restrict__ wt) {
    __shared__ float tile[32][33];
    int z = blockIdx.z;
    const float* W = (z == 0) ? Wq : (z == 1) ? Wk : (z == 2) ? Wv : Wo;
    int n0 = blockIdx.x * 32, k0 = blockIdx.y * 32;
    int tx = threadIdx.x, ty = threadIdx.y;
    tile[ty][tx] = W[(size_t)(k0 + ty) * D_MODEL + n0 + tx];
    __syncthreads();
    wt[(size_t)z * D_MODEL * D_MODEL + (size_t)(n0 + ty) * D_MODEL + k0 + tx] =
        (bf16)tile[tx][ty];
}

// ---------------- GEMM: Y[M,N] = A[M,K] @ Wt[N,K]^T + bias, BK=64 ----------------
// 512 threads / 8 waves (32x64 sub-tile each, acc 2x4). BK=64 halves barrier
// count (16 iters) and doubles per-iter MFMA density (barrier amortization).
// Double-buffered 128B-row LDS (64 KB, 2 blocks/CU = 4 waves/SIMD), counted
// vmcnt(4) 1-deep prefetch. Staging inverse-swizzle (col8 = sl ^ (row&7)) and
// reader slot ((kc*4+hh) ^ (r&7)) both production-proven (attn STAGE / kf,vf).
// MODE0 z==2 (V^T) epilogue via LDS transpose; z==0 scale 0.125*log2e.
template <int MODE>
__global__ __launch_bounds__(512) void gemm_k(const bf16* __restrict__ A,
                                              const bf16* __restrict__ Bt,
                                              const float* __restrict__ b0,
                                              const float* __restrict__ b1,
                                              const float* __restrict__ b2,
                                              void* __restrict__ outp) {
    constexpr int BM = 128, BK = 64, KDIM = D_MODEL;
    __shared__ alignas(16) char SMEM[65536];  // As[2] (32KB) + Bs[2] (32KB); reused as T
    char* Asb = SMEM;
    char* Bsb = SMEM + 32768;
    const int tid = threadIdx.x;
    const int wid = tid >> 6, lane = tid & 63;
    const int m0 = blockIdx.y * BM, n0 = blockIdx.x * BM;
    const int wr = (wid >> 1) * 32, wc = (wid & 1) * 64;
    const int ml = lane & 15, hh = lane >> 4;
    f32x4 acc[2][4] = {};

    // stage one K-tile into buffer BUF: 2 A-chunks + 2 B-chunks per thread.
#define GSTAGE(K0, BUF)                                                       \
    {                                                                         \
        _Pragma("unroll") for (int c = 0; c < 2; ++c) {                       \
            const int chunk = c * 512 + tid;                                  \
            const int row = chunk >> 3, sl = chunk & 7;                       \
            const int col8 = sl ^ (row & 7);                                  \
            GLOAD16(&A[(size_t)(m0 + row) * KDIM + (K0) + col8 * 8],          \
                    Asb + (BUF) * 16384 + chunk * 16);                        \
            GLOAD16(&Bt[(size_t)(n0 + row) * KDIM + (K0) + col8 * 8],         \
                    Bsb + (BUF) * 16384 + chunk * 16);                        \
        }                                                                     \
    }

    GSTAGE(0, 0);
    int cur = 0;
    for (int k0 = 0; k0 < KDIM; k0 += BK) {
        if (k0 + BK < KDIM) {
            GSTAGE(k0 + BK, cur ^ 1);
            asm volatile("s_waitcnt vmcnt(4)" ::: "memory");  // tile k0 landed
        } else {
            asm volatile("s_waitcnt vmcnt(0)" ::: "memory");
        }
        __builtin_amdgcn_s_barrier();

        char* Ab = Asb + cur * 16384;
        char* Bb = Bsb + cur * 16384;
#pragma unroll
        for (int kc = 0; kc < 2; ++kc) {
            bf16x8 a[2], b[4];
#pragma unroll
            for (int m = 0; m < 2; ++m) {
                int r = wr + m * 16 + ml;
                a[m] = *(bf16x8*)(Ab + r * 128 + ((((kc << 2) | hh) ^ (r & 7)) << 4));
            }
#pragma unroll
            for (int n = 0; n < 4; ++n) {
                int r = wc + n * 16 + ml;
                b[n] = *(bf16x8*)(Bb + r * 128 + ((((kc << 2) | hh) ^ (r & 7)) << 4));
            }
#pragma unroll
            for (int m = 0; m < 2; ++m)
#pragma unroll
                for (int n = 0; n < 4; ++n)
                    acc[m][n] =
                        __builtin_amdgcn_mfma_f32_16x16x32_bf16(a[m], b[n], acc[m][n], 0, 0, 0);
        }

        __builtin_amdgcn_s_barrier();
        cur ^= 1;
    }
#undef GSTAGE

    const int z = n0 >> 10;
    const float* bias = (MODE == 1) ? b0 : ((z == 0) ? b0 : (z == 1) ? b1 : b2);

    if (MODE == 0 && z == 2) {
        // V^T epilogue via LDS transpose: coalesced 256B stores
        bf16* T = (bf16*)SMEM;  // [128 nl][128 ml] bf16, swizzled rows (32 KB)
#pragma unroll
        for (int m = 0; m < 2; ++m)
#pragma unroll
            for (int n = 0; n < 4; ++n)
#pragma unroll
                for (int r = 0; r < 4; ++r) {
                    int mll = wr + m * 16 + (lane >> 4) * 4 + r;
                    int nl = wc + n * 16 + ml;
                    float val = acc[m][n][r] + bias[(n0 & 1023) + nl];
                    *(bf16*)((char*)T + nl * 256 + ((2 * mll) ^ ((nl & 7) << 4))) = (bf16)val;
                }
        __builtin_amdgcn_s_barrier();
        const int b_ = m0 >> 11;
        const int s_base = m0 & 2047;
#pragma unroll
        for (int c = 0; c < 4; ++c) {
            int idx = c * 512 + tid;           // 0..2047 = nl(128) x j(16)
            int nl = idx >> 4, j = idx & 15;
            bf16x8 v = *(bf16x8*)((char*)T + nl * 256 + ((16 * j) ^ ((nl & 7) << 4)));
            int colN = (n0 & 1023) + nl;
            int head = colN >> 6, hd = colN & 63;
            *(bf16x8*)&((bf16*)outp)[(size_t)2 * 4194304 +
                                     ((size_t)(b_ * N_HEADS + head) * HEAD_DIM + hd) * SEQ +
                                     s_base + 8 * j] = v;
        }
        return;
    }

#pragma unroll
    for (int m = 0; m < 2; ++m)
#pragma unroll
        for (int n = 0; n < 4; ++n)
#pragma unroll
            for (int r = 0; r < 4; ++r) {
                int grow = m0 + wr + m * 16 + (lane >> 4) * 4 + r;
                int gcol = n0 + wc + n * 16 + ml;
                if (MODE == 0) {
                    int colN = gcol & 1023;
                    float val = acc[m][n][r] + bias[colN];
                    if (z == 0) val *= 0.18033688011112042f;  // 0.125*log2e: exp2 domain
                    int b_ = grow >> 11, s_ = grow & 2047;
                    int h = colN >> 6, hd = colN & 63;
                    ((bf16*)outp)[(size_t)z * 4194304 +
                                  ((size_t)(b_ * N_HEADS + h) * SEQ + s_) * HEAD_DIM + hd] =
                        (bf16)val;
                } else {
                    float val = acc[m][n][r] + bias[gcol];
                    ((float*)outp)[(size_t)grow * D_MODEL + gcol] = val;
                }
            }
}

// ---------------- flash attention: 64-row half-bands + exp2 softmax (R27, 54.3us) ----------------
__global__ __launch_bounds__(256) void attn_k(const bf16* __restrict__ Qg,
                                              const bf16* __restrict__ Kg,
                                              const bf16* __restrict__ VTg,
                                              bf16* __restrict__ AO) {
    __shared__ alignas(16) bf16 Ks[2][64 * 64];         // 16 KB
    __shared__ alignas(16) bf16 Vs[2][64 * 64];         // 16 KB
    __shared__ alignas(16) unsigned int Pk[4][16][32];  // 8 KB
    const int tid = threadIdx.x, wid = tid >> 6, lane = tid & 63;
    const int m = lane & 15, h = lane >> 4;
    const int idx = blockIdx.x;
    const int bh = idx & 31;                // bh%8 fixes XCD -> KV L2 locality
    const int a = (idx >> 5) & 7;
    const int qd = idx >> 8;
    const int hb = (qd == 0) ? (31 - a) : (qd == 1) ? (23 - a) : (qd == 2) ? (8 + a) : a;
    const int q0 = hb * 64 + wid * 16;
    const size_t base = (size_t)bh * SEQ * HEAD_DIM;
    const bf16* VT = VTg + (size_t)bh * HEAD_DIM * SEQ;
    const int swz = (m & 7) << 2;
    const int nt = hb + 1;  // same for all waves in the block

    bf16x8 aq[2];
#pragma unroll
    for (int kc = 0; kc < 2; ++kc)
        aq[kc] = *(const bf16x8*)
            &Qg[base + (size_t)(q0 + m) * HEAD_DIM + kc * 32 + h * 8];

    f32x4 o[4] = {};
    float mrow = -__builtin_inff();
    float lrow = 0.f;

#define STAGE(T0, BUF)                                                            \
    {                                                                             \
        _Pragma("unroll") for (int c = 0; c < 2; ++c) {                           \
            int chunk = c * 256 + tid;                                            \
            int row = chunk >> 3, sl = chunk & 7;                                 \
            GLOAD16(&Kg[base + (size_t)((T0) + row) * HEAD_DIM +                  \
                        8 * (sl ^ (row & 7))],                                    \
                    (char*)&Ks[BUF][0] + chunk * 16);                             \
            GLOAD16(&VT[(size_t)row * SEQ + (T0) + 8 * (sl ^ (row & 7))],         \
                    (char*)&Vs[BUF][0] + chunk * 16);                             \
        }                                                                         \
    }

    STAGE(0, 0);
    int cur = 0;
    for (int it = 0; it < nt; ++it) {
        if (it + 1 < nt) {
            STAGE((it + 1) * 64, cur ^ 1);
            asm volatile("s_waitcnt vmcnt(4)" ::: "memory");  // current tile landed
        } else {
            asm volatile("s_waitcnt vmcnt(0)" ::: "memory");
        }
        __builtin_amdgcn_s_barrier();  // all waves' stage of tile it complete

        {
            const int t0 = it * 64;
            char* Kb = (char*)&Ks[cur][0];
            char* Vb = (char*)&Vs[cur][0];
            bf16x8 kf[4][2], vf[4][2];
#pragma unroll
            for (int tf = 0; tf < 4; ++tf)
#pragma unroll
                for (int kc = 0; kc < 2; ++kc)
                    kf[tf][kc] = *(bf16x8*)(Kb + (16 * tf + m) * 128 +
                                            (((4 * kc + h) ^ (m & 7)) << 4));
#pragma unroll
            for (int nf = 0; nf < 4; ++nf)
#pragma unroll
                for (int kc = 0; kc < 2; ++kc)
                    vf[nf][kc] = *(bf16x8*)(Vb + (16 * nf + m) * 128 +
                                            (((4 * kc + h) ^ (m & 7)) << 4));

            // ---- QK^T swapped: lane holds q=m, t=16tf+4h+r (exp2-domain scores) ----
            f32x4 s[4];
            __builtin_amdgcn_s_setprio(1);
#pragma unroll
            for (int tf = 0; tf < 4; ++tf) {
                f32x4 z = {};
                z = __builtin_amdgcn_mfma_f32_16x16x32_bf16(kf[tf][0], aq[0], z, 0, 0, 0);
                z = __builtin_amdgcn_mfma_f32_16x16x32_bf16(kf[tf][1], aq[1], z, 0, 0, 0);
                s[tf] = z;
            }
            __builtin_amdgcn_s_setprio(0);

            if (it == nt - 1) {
#pragma unroll
                for (int tf = 0; tf < 4; ++tf)
#pragma unroll
                    for (int r = 0; r < 4; ++r) {
                        int gq = q0 + m;
                        int gt = t0 + tf * 16 + h * 4 + r;
                        if (gt > gq) s[tf][r] = -__builtin_inff();
                    }
            }

            // ---- online softmax in exp2 domain (tree reductions, defer-max) ----
            float mt[4];
#pragma unroll
            for (int tf = 0; tf < 4; ++tf)
                mt[tf] = fmaxf(fmaxf(s[tf][0], s[tf][1]), fmaxf(s[tf][2], s[tf][3]));
            float mx = fmaxf(fmaxf(mt[0], mt[1]), fmaxf(mt[2], mt[3]));
            mx = fmaxf(mx, __shfl_xor(mx, 16));
            mx = fmaxf(mx, __shfl_xor(mx, 32));
            if (!__all(mx <= mrow + 11.541560327f)) {  // 8*log2(e)
                float mn = fmaxf(mrow, mx);
                float sf = EXP2F(mrow - mn);
                mrow = mn;
                lrow *= sf;
                float sfr[4];
#pragma unroll
                for (int r = 0; r < 4; ++r) sfr[r] = __shfl(sf, 20 * h + r);
#pragma unroll
                for (int nf = 0; nf < 4; ++nf)
#pragma unroll
                    for (int r = 0; r < 4; ++r) o[nf][r] *= sfr[r];
            }
            float rt[4];
#pragma unroll
            for (int tf = 0; tf < 4; ++tf) {
#pragma unroll
                for (int r = 0; r < 4; ++r) s[tf][r] = EXP2F(s[tf][r] - mrow);
                rt[tf] = (s[tf][0] + s[tf][1]) + (s[tf][2] + s[tf][3]);
            }
            float rs = (rt[0] + rt[1]) + (rt[2] + rt[3]);
            rs += __shfl_xor(rs, 16);
            rs += __shfl_xor(rs, 32);
            lrow += rs;

            // pack P -> wave-private LDS
#pragma unroll
            for (int tf = 0; tf < 4; ++tf)
#pragma unroll
                for (int rp = 0; rp < 2; ++rp) {
                    unsigned int w = ((unsigned int)bfbits(s[tf][2 * rp + 1]) << 16) |
                                     bfbits(s[tf][2 * rp]);
                    Pk[wid][m][(8 * tf + 2 * h + rp) ^ swz] = w;
                }

            // ---- PV ----
            __builtin_amdgcn_s_setprio(1);
#pragma unroll
            for (int kc = 0; kc < 2; ++kc) {
                bf16x8 ap = *(bf16x8*)&Pk[wid][m][(16 * kc + 4 * h) ^ swz];
#pragma unroll
                for (int nf = 0; nf < 4; ++nf)
                    o[nf] = __builtin_amdgcn_mfma_f32_16x16x32_bf16(
                        ap, vf[nf][kc], o[nf], 0, 0, 0);
            }
            __builtin_amdgcn_s_setprio(0);
        }
        __builtin_amdgcn_s_barrier();  // all reads of buf[cur] done; safe to overwrite
        cur ^= 1;
    }
#undef STAGE

    // ---- direct write-out (no merge: waves own distinct q-rows) ----
    const int b_ = bh >> 4, hh = bh & 15;
    float lcr[4];
#pragma unroll
    for (int r = 0; r < 4; ++r) lcr[r] = __shfl(lrow, 20 * h + r);
#pragma unroll
    for (int nf = 0; nf < 4; ++nf)
#pragma unroll
        for (int r = 0; r < 4; ++r) {
            float val = o[nf][r] / lcr[r];
            int s_ = q0 + h * 4 + r;
            AO[((size_t)(b_ * SEQ + s_)) * D_MODEL + hh * HEAD_DIM + nf * 16 + m] =
                (bf16)val;
        }
}

extern "C" void kernel_launch(void* const* d_in, const int* in_sizes, int n_in,
                              void* d_out, int out_size, void* d_ws, size_t ws_size,
                              hipStream_t stream) {
    const float* x  = (const float*)d_in[0];
    const float* Wq = (const float*)d_in[1];
    const float* bq = (const float*)d_in[2];
    const float* Wk = (const float*)d_in[3];
    const float* bk = (const float*)d_in[4];
    const float* Wv = (const float*)d_in[5];
    const float* bv = (const float*)d_in[6];
    const float* Wo = (const float*)d_in[7];
    const float* bo = (const float*)d_in[8];

    char* ws = (char*)d_ws;
    const size_t MB = 1u << 20;
    bf16* wt = (bf16*)ws;                  // 4 x [1024][1024] bf16 (QKV contiguous)
    bf16* xb = (bf16*)(ws + 8 * MB);       // [4096][1024] bf16
    bf16* Qb = (bf16*)(ws + 16 * MB);      // Q*0.125*log2e [32][2048][64]; K; V^T [32][64][2048]
    bf16* AO = (bf16*)(ws + 40 * MB);      // [4096][1024] bf16

    const size_t WSTRIDE = (size_t)D_MODEL * D_MODEL;

    cvt_x<<<dim3(MROWS * D_MODEL / 4 / 256), dim3(256), 0, stream>>>(x, xb);
    cvt_wt<<<dim3(32, 32, 4), dim3(32, 32), 0, stream>>>(Wq, Wk, Wv, Wo, wt);

    gemm_k<0><<<dim3(24, 32), dim3(512), 0, stream>>>(xb, wt, bq, bk, bv, Qb);

    bf16* Kb = Qb + 4194304;
    bf16* VTb = Qb + 2 * 4194304;
    attn_k<<<dim3(1024), dim3(256), 0, stream>>>(Qb, Kb, VTb, AO);

    gemm_k<1><<<dim3(8, 32), dim3(512), 0, stream>>>(AO, wt + 3 * WSTRIDE, bo, bo, bo, d_out);
}